// Round 10
// baseline (536.588 us; speedup 1.0000x reference)
//
#include <hip/hip_runtime.h>
#include <hip/hip_bf16.h>

// B=4, T=4000, D=1024, H=8, DK=128, CHUNK=500, N=T/CHUNK=8
// I/O fp32; internal bf16 with decay prescaled into q/k; fp32 accum.

typedef __attribute__((ext_vector_type(4))) float f32x4;
typedef __attribute__((ext_vector_type(8))) short s16x8;

#define DEV static __device__ __forceinline__

DEV float bfu(ushort u){ union{uint i; float f;} x; x.i=((uint)u)<<16; return x.f; }
DEV ushort f2bf(float f){ union{float f; uint u;} x; x.f=f; uint r = x.u + 0x7fffu + ((x.u>>16)&1u); return (ushort)(r>>16); }
DEV uint pack2(float lo, float hi){ return ((uint)f2bf(hi)<<16) | (uint)f2bf(lo); }

DEV void gload16(const ushort* g, ushort* l) {
  __builtin_amdgcn_global_load_lds((const __attribute__((address_space(1))) void*)g,
                                   (__attribute__((address_space(3))) void*)l, 16, 0, 0);
}

// ---------------- fp32 W[K][N] -> bf16 W^T[N][K], all 5 weights in one launch ----------------
__global__ __launch_bounds__(256) void f2bf_t_all(const float* __restrict__ s0, const float* __restrict__ s1,
                                                  const float* __restrict__ s2, const float* __restrict__ s3,
                                                  const float* __restrict__ s4,
                                                  ushort* __restrict__ d0, ushort* __restrict__ d1,
                                                  ushort* __restrict__ d2, ushort* __restrict__ d3,
                                                  ushort* __restrict__ d4) {
  const float* src; ushort* dst;
  switch (blockIdx.z) {
    case 0: src=s0; dst=d0; break;
    case 1: src=s1; dst=d1; break;
    case 2: src=s2; dst=d2; break;
    case 3: src=s3; dst=d3; break;
    default: src=s4; dst=d4; break;
  }
  __shared__ ushort t[64][72];
  int kt = blockIdx.x*64, nt = blockIdx.y*64;
  int tid = threadIdx.x;
  int r = tid>>2, c0 = (tid&3)*16;
  const float* s = src + (size_t)(kt+r)*1024 + nt + c0;
  #pragma unroll
  for (int j=0;j<16;j+=4) {
    float4 vv = *(const float4*)(s+j);
    t[r][c0+j]=f2bf(vv.x); t[r][c0+j+1]=f2bf(vv.y); t[r][c0+j+2]=f2bf(vv.z); t[r][c0+j+3]=f2bf(vv.w);
  }
  __syncthreads();
  union { uint4 u4[2]; ushort s16[16]; } tmp;
  #pragma unroll
  for (int j=0;j<16;j++) tmp.s16[j] = t[c0+j][r];
  ushort* d = dst + (size_t)(nt+r)*1024 + kt + c0;
  *(uint4*)(d)   = tmp.u4[0];
  *(uint4*)(d+8) = tmp.u4[1];
}

// ---------------- LayerNorm ----------------
__global__ __launch_bounds__(256) void ln_kernel(const float* __restrict__ x,
                                                 const float* __restrict__ gamma,
                                                 const float* __restrict__ beta,
                                                 ushort* __restrict__ xo) {
  int row = blockIdx.x;
  int tid = threadIdx.x;
  const float* xr = x + (size_t)row*1024;
  float4 u = ((const float4*)xr)[tid];
  float s = u.x+u.y+u.z+u.w;
  float sq = u.x*u.x+u.y*u.y+u.z*u.z+u.w*u.w;
  #pragma unroll
  for (int o=32;o;o>>=1){ s += __shfl_xor(s,o); sq += __shfl_xor(sq,o); }
  __shared__ float red[8];
  int wv=tid>>6, ln=tid&63;
  if (ln==0){ red[wv]=s; red[4+wv]=sq; }
  __syncthreads();
  s = red[0]+red[1]+red[2]+red[3];
  sq = red[4]+red[5]+red[6]+red[7];
  float mu = s*(1.0f/1024.0f);
  float var = sq*(1.0f/1024.0f)-mu*mu;
  float inv = rsqrtf(var+1e-5f);
  float4 gg = ((const float4*)gamma)[tid];
  float4 bb = ((const float4*)beta)[tid];
  float o0=(u.x-mu)*inv*gg.x+bb.x;
  float o1=(u.y-mu)*inv*gg.y+bb.y;
  float o2=(u.z-mu)*inv*gg.z+bb.z;
  float o3=(u.w-mu)*inv*gg.w+bb.w;
  uint2 w; w.x=pack2(o0,o1); w.y=pack2(o2,o3);
  ((uint2*)(xo+(size_t)row*1024))[tid]=w;
}

// ---------------- sin/cos tables [4000][128] fp32 ----------------
__global__ __launch_bounds__(256) void sincos_kernel(float* __restrict__ sint, float* __restrict__ cost) {
  int idx = blockIdx.x*256+threadIdx.x;
  if (idx >= 4000*64) return;
  int t = idx>>6, i = idx&63;
  float ang = expf(-9.210340371976184f * (float)i * (1.0f/63.0f));
  float a = (float)t * ang;
  float sv = sinf(a), cv = cosf(a);
  sint[(size_t)t*128+2*i] = sv; sint[(size_t)t*128+2*i+1] = sv;
  cost[(size_t)t*128+2*i] = cv; cost[(size_t)t*128+2*i+1] = cv;
}

// ======== fused projection GEMM: 256x128 tile, 8 waves, B-resident XCD mapping ========
// XCD x owns n-panels {4x..4x+3} (1MB L2-resident); 4 consecutive blocks share an A m-tile.
// proj 0: q rot+prescale  1: k rot+scale + kT  2: vT only  3: g plain
__global__ __launch_bounds__(512) void gemm_proj(const ushort* __restrict__ A,
                                                 const ushort* __restrict__ BT,
                                                 ushort* __restrict__ qb,
                                                 ushort* __restrict__ kb,
                                                 ushort* __restrict__ gb,
                                                 ushort* __restrict__ kT,
                                                 ushort* __restrict__ vT,
                                                 const float* __restrict__ sint,
                                                 const float* __restrict__ cost) {
  __attribute__((aligned(16))) __shared__ char smem[49152];  // 2 bufs x (A 16KB + B 8KB)
  const int K = 1024;
  int wg = blockIdx.x;                 // 2016 blocks
  int x = wg&7;                        // XCD
  int i = wg>>3;                       // 0..251
  int nloc = i&3, mt = i>>2;           // mt 0..62
  int bm = mt*256;
  int bn = (x*4+nloc)*128;
  int tid = threadIdx.x;
  int w = tid>>6, l = tid&63;
  int wr = w>>1, wc = w&1;
  int wm = wr*64, wn = wc*64;
  int rsel = l&15, ko = (l>>4)*8;
  f32x4 acc[4][4];
  #pragma unroll
  for (int a2=0;a2<4;a2++)
    #pragma unroll
    for (int j=0;j<4;j++){ acc[a2][j][0]=0; acc[a2][j][1]=0; acc[a2][j][2]=0; acc[a2][j][3]=0; }
  int arow0 = bm + w*16 + (l>>2);                  // 0..127 of tile (always < 16000)
  int arow1 = arow0 + 128; if (arow1 > 15999) arow1 = 15999;   // mt=62 tail clamp
  const ushort* ap0 = A + (size_t)arow0*K + (l&3)*8;
  const ushort* ap1 = A + (size_t)arow1*K + (l&3)*8;
  const ushort* bp0 = BT + (size_t)(bn + w*16 + (l>>2))*K + (l&3)*8;
  {
    char* buf = smem;
    gload16(ap0, (ushort*)(buf + w*1024));
    gload16(ap1, (ushort*)(buf + 8192 + w*1024));
    gload16(bp0, (ushort*)(buf + 16384 + w*1024));
  }
  int cur = 0;
  for (int kt=0; kt<K; kt+=32) {
    __syncthreads();
    if (kt+32 < K) {
      char* buf = smem + (cur^1)*24576;
      gload16(ap0+kt+32, (ushort*)(buf + w*1024));
      gload16(ap1+kt+32, (ushort*)(buf + 8192 + w*1024));
      gload16(bp0+kt+32, (ushort*)(buf + 16384 + w*1024));
    }
    const ushort* Ac = (const ushort*)(smem + cur*24576);
    const ushort* Bc = (const ushort*)(smem + cur*24576 + 16384);
    s16x8 af[4], bfr[4];
    #pragma unroll
    for (int mf=0;mf<4;mf++) af[mf]  = *(const s16x8*)&Ac[(wm+mf*16+rsel)*32 + ko];
    #pragma unroll
    for (int nf=0;nf<4;nf++) bfr[nf] = *(const s16x8*)&Bc[(wn+nf*16+rsel)*32 + ko];
    #pragma unroll
    for (int mf=0;mf<4;mf++)
      #pragma unroll
      for (int nf=0;nf<4;nf++)
        acc[mf][nf] = __builtin_amdgcn_mfma_f32_16x16x32_bf16(af[mf], bfr[nf], acc[mf][nf], 0,0,0);
    cur ^= 1;
  }
  // ---- LDS-staged epilogue, two 128-row halves ----
  int proj = bn>>10;            // block-uniform
  int bnp  = bn&1023;
  int hh   = bnp>>7;
  __syncthreads();
  ushort* Ct = (ushort*)smem;   // [128][136]
  #pragma unroll
  for (int hf=0; hf<2; hf++) {
    if ((wr>>1)==hf) {
      int rbase = (wr&1)*64;
      if (proj < 2) {
        float decay = logf(1.0f - exp2f(-5.0f-(float)hh));
        float ksc = 0.08838834764831845f;
        #pragma unroll
        for (int mf=0;mf<4;mf++) {
          #pragma unroll
          for (int r2=0;r2<4;r2++) {
            int rowt = rbase + mf*16 + (l>>4)*4 + r2;
            int grow = bm + hf*128 + rowt;
            int t = grow - (grow/4000)*4000;
            int cch = t - (t/500)*500;
            float esc = (proj==0)? expf(decay*(float)cch) : expf(-decay*(float)cch)*ksc;
            const float* ctab = cost + (size_t)t*128;
            const float* stab = sint + (size_t)t*128;
            #pragma unroll
            for (int nf=0;nf<4;nf++) {
              int colt = wn + nf*16 + (l&15);
              float vv = acc[mf][nf][r2];
              float cc = ctab[colt], ss = stab[colt];
              float ov = __shfl_xor(vv,1);
              float rot = ((l&1)==0)? (vv*cc-ov*ss) : (vv*cc+ov*ss);
              Ct[rowt*136+colt] = f2bf(rot*esc);
            }
          }
        }
      } else {
        #pragma unroll
        for (int mf=0;mf<4;mf++)
          #pragma unroll
          for (int nf=0;nf<4;nf++) {
            int colt = wn + nf*16 + (l&15);
            #pragma unroll
            for (int r2=0;r2<4;r2++)
              Ct[(rbase+mf*16+(l>>4)*4+r2)*136+colt] = f2bf(acc[mf][nf][r2]);
          }
      }
    }
    __syncthreads();
    if (proj != 2) {
      ushort* dst = (proj==0)? qb : (proj==1)? kb : gb;
      int r = tid>>2, ch=(tid&3)*32;
      int grow = bm + hf*128 + r;
      if (grow < 16000) {
        ushort* drow = dst + (size_t)grow*1024 + bnp + ch;
        #pragma unroll
        for (int j=0;j<4;j++) *(uint4*)(drow+j*8) = *(uint4*)&Ct[r*136+ch+j*8];
      }
    }
    if (proj==1 || proj==2) {
      ushort* Tdst = (proj==1)? kT : vT;
      int dloc = tid>>2, rh=(tid&3)*32;
      #pragma unroll
      for (int j=0;j<4;j++) {
        int gr = bm + hf*128 + rh + j*8;
        if (gr < 16000) {
          int bb = gr/4000; int t0 = gr - bb*4000;
          int ch0 = t0/500; int c0 = t0 - ch0*500;
          if (c0 <= 492) {
            union{uint4 u; ushort s[8];} pk;
            #pragma unroll
            for (int ii=0;ii<8;ii++) pk.s[ii] = Ct[(rh+j*8+ii)*136 + dloc];
            *(uint4*)(Tdst + ((size_t)(bb*64+ch0*8+hh))*65536 + (size_t)dloc*512 + c0) = pk.u;
          } else {
            #pragma unroll
            for (int ii=0;ii<8;ii++) {
              int gri = gr+ii; int bbi=gri/4000; int ti=gri-bbi*4000; int chi=ti/500; int ci=ti-chi*500;
              Tdst[((size_t)(bbi*64+chi*8+hh))*65536 + (size_t)dloc*512 + ci] = Ct[(rh+j*8+ii)*136+dloc];
            }
          }
        }
      }
    }
    __syncthreads();
  }
}

// ======== final GEMM: 256x128 tile, 8 waves, XCD owns one Wo n-panel; fp32 epilogue ========
__global__ __launch_bounds__(512) void gemm_out(const ushort* __restrict__ A,
                                                const ushort* __restrict__ BT,
                                                float* __restrict__ C) {
  __attribute__((aligned(16))) __shared__ char smem[49152];
  const int K = 1024;
  int wg = blockIdx.x;                 // 504 blocks
  int x = wg&7;
  int mt = wg>>3;                      // 0..62
  int bm = mt*256, bn = x*128;
  int tid = threadIdx.x;
  int w = tid>>6, l = tid&63;
  int wr = w>>1, wc = w&1;
  int wm = wr*64, wn = wc*64;
  int rsel = l&15, ko = (l>>4)*8;
  f32x4 acc[4][4];
  #pragma unroll
  for (int a2=0;a2<4;a2++)
    #pragma unroll
    for (int j=0;j<4;j++){ acc[a2][j][0]=0; acc[a2][j][1]=0; acc[a2][j][2]=0; acc[a2][j][3]=0; }
  int arow0 = bm + w*16 + (l>>2);
  int arow1 = arow0 + 128; if (arow1 > 15999) arow1 = 15999;
  const ushort* ap0 = A + (size_t)arow0*K + (l&3)*8;
  const ushort* ap1 = A + (size_t)arow1*K + (l&3)*8;
  const ushort* bp0 = BT + (size_t)(bn + w*16 + (l>>2))*K + (l&3)*8;
  {
    char* buf = smem;
    gload16(ap0, (ushort*)(buf + w*1024));
    gload16(ap1, (ushort*)(buf + 8192 + w*1024));
    gload16(bp0, (ushort*)(buf + 16384 + w*1024));
  }
  int cur = 0;
  for (int kt=0; kt<K; kt+=32) {
    __syncthreads();
    if (kt+32 < K) {
      char* buf = smem + (cur^1)*24576;
      gload16(ap0+kt+32, (ushort*)(buf + w*1024));
      gload16(ap1+kt+32, (ushort*)(buf + 8192 + w*1024));
      gload16(bp0+kt+32, (ushort*)(buf + 16384 + w*1024));
    }
    const ushort* Ac = (const ushort*)(smem + cur*24576);
    const ushort* Bc = (const ushort*)(smem + cur*24576 + 16384);
    s16x8 af[4], bfr[4];
    #pragma unroll
    for (int mf=0;mf<4;mf++) af[mf]  = *(const s16x8*)&Ac[(wm+mf*16+rsel)*32 + ko];
    #pragma unroll
    for (int nf=0;nf<4;nf++) bfr[nf] = *(const s16x8*)&Bc[(wn+nf*16+rsel)*32 + ko];
    #pragma unroll
    for (int mf=0;mf<4;mf++)
      #pragma unroll
      for (int nf=0;nf<4;nf++)
        acc[mf][nf] = __builtin_amdgcn_mfma_f32_16x16x32_bf16(af[mf], bfr[nf], acc[mf][nf], 0,0,0);
    cur ^= 1;
  }
  __syncthreads();
  float* Cf = (float*)smem;  // [64][132]
  #pragma unroll
  for (int qf=0; qf<4; qf++) {
    if (wr==qf) {
      #pragma unroll
      for (int mf=0;mf<4;mf++)
        #pragma unroll
        for (int nf=0;nf<4;nf++)
          #pragma unroll
          for (int r2=0;r2<4;r2++)
            Cf[(mf*16+(l>>4)*4+r2)*132 + wn+nf*16+(l&15)] = acc[mf][nf][r2];
    }
    __syncthreads();
    {
      int r = tid>>3, cs=(tid&7)*16;
      int grow = bm + qf*64 + r;
      if (grow < 16000) {
        float* drow = C + (size_t)grow*1024 + bn + cs;
        #pragma unroll
        for (int j=0;j<4;j++) *(float4*)(drow+j*4) = *(float4*)&Cf[r*132+cs+j*4];
      }
    }
    __syncthreads();
  }
}

// ---- MFMA kv: kvp[bnh][dk][dv] = sum_c kT[dk][c]*vT[dv][c] (decay via prescale) ----
__global__ __launch_bounds__(256) void kv_mfma(const ushort* __restrict__ kT,
                                               const ushort* __restrict__ vT,
                                               float* __restrict__ kvp) {
  int bnh = blockIdx.x;
  __shared__ ushort sh2[16384];
  int tid=threadIdx.x;
  int wv=tid>>6, l=tid&63, g=l>>4, c16=l&15;
  int wr = wv>>1, wc = wv&1;
  int ri[4], ro[4];
  #pragma unroll
  for (int jj=0;jj<4;jj++){
    int i = wv*256 + jj*64 + l;
    ri[jj] = i>>3;
    ro[jj] = (((i&7)*16) ^ ((ri[jj]&7)<<4))>>1;
  }
  const ushort* kbase = kT + (size_t)bnh*65536;
  const ushort* vbase = vT + (size_t)bnh*65536;
  f32x4 acc[4][4];
  #pragma unroll
  for (int i=0;i<4;i++)
    #pragma unroll
    for (int j=0;j<4;j++){ acc[i][j][0]=0; acc[i][j][1]=0; acc[i][j][2]=0; acc[i][j][3]=0; }
  for (int ctep=0; ctep<8; ctep++) {
    int cb = ctep*64;
    __syncthreads();
    #pragma unroll
    for (int jj=0;jj<4;jj++){
      gload16(kbase + (size_t)ri[jj]*512 + cb + ro[jj], (ushort*)((char*)sh2 + wv*4096 + jj*1024));
      gload16(vbase + (size_t)ri[jj]*512 + cb + ro[jj], (ushort*)((char*)sh2 + 16384 + wv*4096 + jj*1024));
    }
    __syncthreads();
    if (ctep==7) {
      for (int z=tid; z<128*12; z+=256) {
        int r = z/12, j = 52 + (z - (z/12)*12);
        *(ushort*)((char*)sh2 + 16384 + r*128 + ((j*2) ^ ((r&7)<<4))) = 0;
      }
      __syncthreads();
    }
    #pragma unroll
    for (int kc=0;kc<2;kc++) {
      s16x8 af[4], bf2[4];
      #pragma unroll
      for (int mf=0;mf<4;mf++){
        int row = wr*64+mf*16+c16;
        af[mf] = *(const s16x8*)((const char*)sh2 + row*128 + ((((kc*32+g*8)*2)) ^ ((row&7)<<4)));
      }
      #pragma unroll
      for (int nf=0;nf<4;nf++){
        int row = wc*64+nf*16+c16;
        bf2[nf] = *(const s16x8*)((const char*)sh2 + 16384 + row*128 + ((((kc*32+g*8)*2)) ^ ((row&7)<<4)));
      }
      #pragma unroll
      for (int mf=0;mf<4;mf++)
        #pragma unroll
        for (int nf=0;nf<4;nf++)
          acc[mf][nf] = __builtin_amdgcn_mfma_f32_16x16x32_bf16(af[mf], bf2[nf], acc[mf][nf], 0,0,0);
    }
  }
  float* outp = kvp + (size_t)bnh*16384;
  #pragma unroll
  for (int mf=0;mf<4;mf++)
    #pragma unroll
    for (int nf=0;nf<4;nf++)
      #pragma unroll
      for (int reg=0;reg<4;reg++)
        outp[(size_t)(wr*64+mf*16+g*4+reg)*128 + wc*64+nf*16+c16] = acc[mf][nf][reg];
}

// ------- scan: st = st*cd + cst*kv_i ; kvrecT bf16 [dv][dk] -------
__global__ __launch_bounds__(256) void scan_kernel(const float* __restrict__ kvp,
                                                   ushort* __restrict__ kvrecT,
                                                   float* __restrict__ crosssc) {
  int bh = blockIdx.x;
  int b = bh>>3, h = bh&7;
  float Dh = 1.0f - exp2f(-5.0f-(float)h);
  float decay = logf(Dh);
  float cd = expf(decay*500.0f);
  float ls = (1.0f - expf(decay*500.0f))/(1.0f-Dh);
  float cst = expf(decay*499.0f)/ls;
  int tid=threadIdx.x;
  int vcol = tid&127, khalf = tid>>7;
  float st[64];
  #pragma unroll
  for (int i=0;i<64;i++) st[i]=0;
  float scale = 1.0f;
  __shared__ float colpart[2][128];
  __shared__ float sred[2];
  for (int n=0;n<8;n++) {
    int bnh = (b*8+n)*8+h;
    const float* src = kvp + (size_t)bnh*16384;
    ushort* rec = kvrecT + (size_t)bnh*16384;
    float inv = 1.0f/scale;
    float cs = 0;
    #pragma unroll
    for (int i=0;i<64;i++) {
      int kk = khalf*64+i;
      rec[(size_t)vcol*128+kk] = f2bf(st[i]*inv);
      st[i] = st[i]*cd + cst*src[(size_t)kk*128+vcol];
      cs += fabsf(st[i]);
    }
    if (tid==0) crosssc[bnh] = scale;
    colpart[khalf][vcol] = cs;
    __syncthreads();
    if (tid<128) colpart[0][tid] += colpart[1][tid];
    __syncthreads();
    float m = (tid<128)? colpart[0][tid] : 0.0f;
    #pragma unroll
    for (int o=32;o;o>>=1) m = fmaxf(m,__shfl_xor(m,o));
    if (tid<128 && (tid&63)==0) sred[tid>>6]=m;
    __syncthreads();
    scale = fmaxf(fmaxf(sred[0],sred[1]),1.0f);
    __syncthreads();
  }
}

// ---- retention core, XCD-grouped grid ----
__global__ __launch_bounds__(256,4) void iout_mfma(const ushort* __restrict__ qr,
                                                   const ushort* __restrict__ kr,
                                                   const ushort* __restrict__ vT,
                                                   const ushort* __restrict__ kvrecT,
                                                   const float* __restrict__ crosssc,
                                                   const ushort* __restrict__ gbuf,
                                                   ushort* __restrict__ opre) {
  int ib = blockIdx.x;
  int x = ib&7, u = ib>>3;
  int rt = u&7;
  int bnh = x*32 + (u>>3);
  int h = bnh&7, n=(bnh>>3)&7, b=bnh>>6;
  size_t base = (size_t)(b*4000+n*500)*1024 + h*128;
  float Dh = 1.0f - exp2f(-5.0f-(float)h);
  float decay = logf(Dh);
  __shared__ ushort sh[20480];
  char* shb = (char*)sh;
  int tid = threadIdx.x;
  int wv = tid>>6, l = tid&63;
  int g = l>>4, c16 = l&15;
  int r_base = rt*64 + wv*16 + g*4;

  int qrow = rt*64 + wv*16 + c16; if (qrow>499) qrow=499;
  s16x8 aq[4];
  #pragma unroll
  for (int kc=0;kc<4;kc++)
    aq[kc] = *(const s16x8*)(qr + base + (size_t)qrow*1024 + kc*32 + g*8);

  int ktrow[4], ktofs[4], vtrow[4], vtofs[4];
  #pragma unroll
  for (int jj=0;jj<4;jj++){
    int i = wv*256 + jj*64 + l;
    int r_ = i>>4;  ktrow[jj]=r_;  ktofs[jj] = (((i&15)*16) ^ ((r_&7)<<4))>>1;
    int r2_ = i>>3; vtrow[jj]=r2_; vtofs[jj] = (((i&7)*16) ^ ((r2_&7)<<4))>>1;
  }
  const ushort* vTb = vT + (size_t)bnh*65536;

  f32x4 pv[8], cc[8];
  #pragma unroll
  for (int i=0;i<8;i++){
    #pragma unroll
    for (int j=0;j<4;j++){ pv[i][j]=0.0f; cc[i][j]=0.0f; }
  }
  float rowsum[4] = {0,0,0,0};

  for (int et=0; et<=rt; et++) {
    __syncthreads();
    #pragma unroll
    for (int jj=0;jj<4;jj++){
      int gr = et*64 + ktrow[jj]; if (gr>499) gr=499;
      gload16(kr + base + (size_t)gr*1024 + ktofs[jj], (ushort*)(shb + wv*4096 + jj*1024));
      gload16(vTb + (size_t)vtrow[jj]*512 + et*64 + vtofs[jj], (ushort*)(shb + 16384 + wv*4096 + jj*1024));
    }
    __syncthreads();
    f32x4 S[4];
    #pragma unroll
    for (int i=0;i<4;i++){ S[i][0]=0; S[i][1]=0; S[i][2]=0; S[i][3]=0; }
    __builtin_amdgcn_s_setprio(1);
    #pragma unroll
    for (int kc=0;kc<4;kc++) {
      #pragma unroll
      for (int ni=0;ni<4;ni++) {
        int krow = ni*16+c16;
        s16x8 bf = *(const s16x8*)(shb + krow*256 + ((((kc*32+g*8)*2)) ^ ((krow&7)<<4)));
        S[ni] = __builtin_amdgcn_mfma_f32_16x16x32_bf16(aq[kc], bf, S[ni], 0,0,0);
      }
    }
    __builtin_amdgcn_s_setprio(0);
    bool diag = (et==rt);
    #pragma unroll
    for (int ni=0;ni<4;ni++) {
      int e_rel = et*64 + ni*16 + c16;
      #pragma unroll
      for (int reg=0;reg<4;reg++) {
        float p = S[ni][reg];
        if (diag && e_rel > r_base+reg) p = 0.0f;
        rowsum[reg] += fabsf(p);
        int prow = wv*16 + g*4 + reg;
        *(ushort*)(shb + 32768 + prow*128 + (((ni*16+c16)*2) ^ ((prow&7)<<4))) = f2bf(p);
      }
    }
    __builtin_amdgcn_s_setprio(1);
    #pragma unroll
    for (int kc=0;kc<2;kc++) {
      int prow = wv*16 + c16;
      s16x8 pa = *(const s16x8*)(shb + 32768 + prow*128 + ((((kc*32+g*8)*2)) ^ ((prow&7)<<4)));
      #pragma unroll
      for (int nf=0;nf<8;nf++) {
        int vrow = nf*16+c16;
        s16x8 vb = *(const s16x8*)(shb + 16384 + vrow*128 + ((((kc*32+g*8)*2)) ^ ((vrow&7)<<4)));
        pv[nf] = __builtin_amdgcn_mfma_f32_16x16x32_bf16(pa, vb, pv[nf], 0,0,0);
      }
    }
    __builtin_amdgcn_s_setprio(0);
  }
  #pragma unroll
  for (int reg=0;reg<4;reg++) {
    float s = rowsum[reg];
    s += __shfl_xor(s,1); s += __shfl_xor(s,2); s += __shfl_xor(s,4); s += __shfl_xor(s,8);
    rowsum[reg] = s;
  }
  __syncthreads();
  #pragma unroll
  for (int jj=0;jj<8;jj++){
    int i = wv*512 + jj*64 + l;
    int r_ = i>>4;
    int ofs = (((i&15)*16) ^ ((r_&7)<<4))>>1;
    gload16(kvrecT + (size_t)bnh*16384 + (size_t)r_*128 + ofs, (ushort*)(shb + wv*8192 + jj*1024));
  }
  __syncthreads();
  __builtin_amdgcn_s_setprio(1);
  #pragma unroll
  for (int kc=0;kc<4;kc++) {
    #pragma unroll
    for (int nf=0;nf<8;nf++) {
      int krow = nf*16+c16;
      s16x8 bb = *(const s16x8*)(shb + krow*256 + ((((kc*32+g*8)*2)) ^ ((krow&7)<<4)));
      cc[nf] = __builtin_amdgcn_mfma_f32_16x16x32_bf16(aq[kc], bb, cc[nf], 0,0,0);
    }
  }
  __builtin_amdgcn_s_setprio(0);
  float cs = crosssc[bnh];
  float lsum = (1.0f-expf(decay*500.0f))/(1.0f-Dh);
  float ed = expf(decay);
  #pragma unroll
  for (int reg=0;reg<4;reg++) {
    int rr = r_base + reg;
    if (rr < 500) {
      float rs = (1.0f-expf(decay*(float)(rr+1)))/(1.0f-Dh);
      float rsr = rsqrtf(rs);
      float is = fmaxf(1.0f, rowsum[reg]*rsr);
      float all = fmaxf(is, cs);
      float qid = ed*lsum*rsr;
      float fi = rsr/all;
      float fc = qid*(cs/all);
      float o[8]; float ssq = 0.0f;
      #pragma unroll
      for (int nf=0;nf<8;nf++){ o[nf] = pv[nf][reg]*fi + cc[nf][reg]*fc; ssq += o[nf]*o[nf]; }
      ssq += __shfl_xor(ssq,1); ssq += __shfl_xor(ssq,2); ssq += __shfl_xor(ssq,4); ssq += __shfl_xor(ssq,8);
      float rmss = rsqrtf(ssq*(1.0f/128.0f)+1e-6f);
      size_t rowoff = (size_t)(b*4000+n*500+rr)*1024 + h*128;
      #pragma unroll
      for (int nf=0;nf<8;nf++){
        float gv = bfu(gbuf[rowoff + nf*16 + c16]);
        float sg = gv/(1.0f+expf(-gv));
        opre[rowoff + nf*16 + c16] = f2bf(sg*o[nf]*rmss);
      }
    }
  }
}

extern "C" void kernel_launch(void* const* d_in, const int* in_sizes, int n_in,
                              void* d_out, int out_size, void* d_ws, size_t ws_size,
                              hipStream_t stream) {
  const float* x     = (const float*)d_in[0];
  const float* gamma = (const float*)d_in[1];
  const float* beta  = (const float*)d_in[2];
  const float* Wq    = (const float*)d_in[3];
  const float* Wk    = (const float*)d_in[4];
  const float* Wv    = (const float*)d_in[5];
  const float* Wg    = (const float*)d_in[6];
  const float* Wo    = (const float*)d_in[7];
  float* out = (float*)d_out;

  char* ws = (char*)d_ws;
  size_t off = 0;
  auto alloc = [&](size_t bytes)->void* { void* p = ws+off; off += (bytes+255)&~(size_t)255; return p; };
  const size_t BT1024 = (size_t)16000*1024;
  ushort* xln  = (ushort*)alloc(BT1024*2);   // reused: kvp (fp32, 16.8MB) then opre
  ushort* q    = (ushort*)alloc(BT1024*2);
  ushort* k    = (ushort*)alloc(BT1024*2);
  ushort* g    = (ushort*)alloc(BT1024*2);
  // NOTE: WqT..WgT MUST be contiguous (fused GEMM treats them as one [4096][1024])
  ushort* WqT  = (ushort*)alloc((size_t)1024*1024*2);
  ushort* WkT  = (ushort*)alloc((size_t)1024*1024*2);
  ushort* WvT  = (ushort*)alloc((size_t)1024*1024*2);
  ushort* WgT  = (ushort*)alloc((size_t)1024*1024*2);
  ushort* WoT  = (ushort*)alloc((size_t)1024*1024*2);
  float* sint  = (float*)alloc((size_t)4000*128*4);
  float* cost  = (float*)alloc((size_t)4000*128*4);
  ushort* kT   = (ushort*)alloc((size_t)256*65536*2);
  ushort* vT   = (ushort*)alloc((size_t)256*65536*2);
  ushort* kvrecT=(ushort*)alloc((size_t)256*16384*2);
  float* crosssc = (float*)alloc(256*4);
  (void)ws_size; (void)in_sizes; (void)n_in; (void)out_size;

  ln_kernel<<<16000,256,0,stream>>>(x,gamma,beta,xln);
  sincos_kernel<<<1000,256,0,stream>>>(sint,cost);
  dim3 tt(16,16,5);
  f2bf_t_all<<<tt,256,0,stream>>>(Wq,Wk,Wv,Wg,Wo, WqT,WkT,WvT,WgT,WoT);

  // one fused projection GEMM: BT = [WqT;WkT;WvT;WgT] (contiguous), 256x128 tiles
  gemm_proj<<<2016,512,0,stream>>>(xln, WqT, q, k, g, kT, vT, sint, cost);

  float* kvp = (float*)xln;   // xln dead after projections
  kv_mfma<<<256,256,0,stream>>>(kT,vT,kvp);
  scan_kernel<<<32,256,0,stream>>>(kvp,kvrecT,crosssc);

  ushort* opre = xln;         // kvp dead after scan
  iout_mfma<<<2048,256,0,stream>>>(q,k,vT,kvrecT,crosssc,g,opre);

  gemm_out<<<504,512,0,stream>>>(opre,WoT,out);
}

// Round 11
// 446.973 us; speedup vs baseline: 1.2005x; 1.2005x over previous
//
#include <hip/hip_runtime.h>
#include <hip/hip_bf16.h>

// B=4, T=4000, D=1024, H=8, DK=128, CHUNK=500, N=T/CHUNK=8
// I/O fp32; internal bf16 with decay prescaled into q/k; fp32 accum.

typedef __attribute__((ext_vector_type(4))) float f32x4;
typedef __attribute__((ext_vector_type(8))) short s16x8;

#define DEV static __device__ __forceinline__

DEV float bfu(ushort u){ union{uint i; float f;} x; x.i=((uint)u)<<16; return x.f; }
DEV ushort f2bf(float f){ union{float f; uint u;} x; x.f=f; uint r = x.u + 0x7fffu + ((x.u>>16)&1u); return (ushort)(r>>16); }
DEV uint pack2(float lo, float hi){ return ((uint)f2bf(hi)<<16) | (uint)f2bf(lo); }

DEV void gload16(const ushort* g, ushort* l) {
  __builtin_amdgcn_global_load_lds((const __attribute__((address_space(1))) void*)g,
                                   (__attribute__((address_space(3))) void*)l, 16, 0, 0);
}

// ---------------- fp32 W[K][N] -> bf16 W^T[N][K], all 5 weights in one launch ----------------
__global__ __launch_bounds__(256) void f2bf_t_all(const float* __restrict__ s0, const float* __restrict__ s1,
                                                  const float* __restrict__ s2, const float* __restrict__ s3,
                                                  const float* __restrict__ s4,
                                                  ushort* __restrict__ d0, ushort* __restrict__ d1,
                                                  ushort* __restrict__ d2, ushort* __restrict__ d3,
                                                  ushort* __restrict__ d4) {
  const float* src; ushort* dst;
  switch (blockIdx.z) {
    case 0: src=s0; dst=d0; break;
    case 1: src=s1; dst=d1; break;
    case 2: src=s2; dst=d2; break;
    case 3: src=s3; dst=d3; break;
    default: src=s4; dst=d4; break;
  }
  __shared__ ushort t[64][72];
  int kt = blockIdx.x*64, nt = blockIdx.y*64;
  int tid = threadIdx.x;
  int r = tid>>2, c0 = (tid&3)*16;
  const float* s = src + (size_t)(kt+r)*1024 + nt + c0;
  #pragma unroll
  for (int j=0;j<16;j+=4) {
    float4 vv = *(const float4*)(s+j);
    t[r][c0+j]=f2bf(vv.x); t[r][c0+j+1]=f2bf(vv.y); t[r][c0+j+2]=f2bf(vv.z); t[r][c0+j+3]=f2bf(vv.w);
  }
  __syncthreads();
  union { uint4 u4[2]; ushort s16[16]; } tmp;
  #pragma unroll
  for (int j=0;j<16;j++) tmp.s16[j] = t[c0+j][r];
  ushort* d = dst + (size_t)(nt+r)*1024 + kt + c0;
  *(uint4*)(d)   = tmp.u4[0];
  *(uint4*)(d+8) = tmp.u4[1];
}

// ---------------- LayerNorm ----------------
__global__ __launch_bounds__(256) void ln_kernel(const float* __restrict__ x,
                                                 const float* __restrict__ gamma,
                                                 const float* __restrict__ beta,
                                                 ushort* __restrict__ xo) {
  int row = blockIdx.x;
  int tid = threadIdx.x;
  const float* xr = x + (size_t)row*1024;
  float4 u = ((const float4*)xr)[tid];
  float s = u.x+u.y+u.z+u.w;
  float sq = u.x*u.x+u.y*u.y+u.z*u.z+u.w*u.w;
  #pragma unroll
  for (int o=32;o;o>>=1){ s += __shfl_xor(s,o); sq += __shfl_xor(sq,o); }
  __shared__ float red[8];
  int wv=tid>>6, ln=tid&63;
  if (ln==0){ red[wv]=s; red[4+wv]=sq; }
  __syncthreads();
  s = red[0]+red[1]+red[2]+red[3];
  sq = red[4]+red[5]+red[6]+red[7];
  float mu = s*(1.0f/1024.0f);
  float var = sq*(1.0f/1024.0f)-mu*mu;
  float inv = rsqrtf(var+1e-5f);
  float4 gg = ((const float4*)gamma)[tid];
  float4 bb = ((const float4*)beta)[tid];
  float o0=(u.x-mu)*inv*gg.x+bb.x;
  float o1=(u.y-mu)*inv*gg.y+bb.y;
  float o2=(u.z-mu)*inv*gg.z+bb.z;
  float o3=(u.w-mu)*inv*gg.w+bb.w;
  uint2 w; w.x=pack2(o0,o1); w.y=pack2(o2,o3);
  ((uint2*)(xo+(size_t)row*1024))[tid]=w;
}

// ---------------- sin/cos tables [4000][128] fp32 ----------------
__global__ __launch_bounds__(256) void sincos_kernel(float* __restrict__ sint, float* __restrict__ cost) {
  int idx = blockIdx.x*256+threadIdx.x;
  if (idx >= 4000*64) return;
  int t = idx>>6, i = idx&63;
  float ang = expf(-9.210340371976184f * (float)i * (1.0f/63.0f));
  float a = (float)t * ang;
  float sv = sinf(a), cv = cosf(a);
  sint[(size_t)t*128+2*i] = sv; sint[(size_t)t*128+2*i+1] = sv;
  cost[(size_t)t*128+2*i] = cv; cost[(size_t)t*128+2*i+1] = cv;
}

// ======== fused projection GEMM: A[16000x1024] @ BT[4096x1024]^T, 4 outputs ========
// 128x128 tile, 256 thr (round-9 structure) + B-resident XCD mapping:
// XCD x owns n-panels {4x..4x+3} (1MB L2-resident); 4 consecutive blocks share an A m-panel.
__global__ __launch_bounds__(256) void gemm_proj(const ushort* __restrict__ A,
                                                 const ushort* __restrict__ BT,
                                                 ushort* __restrict__ qb,
                                                 ushort* __restrict__ kb,
                                                 ushort* __restrict__ gb,
                                                 ushort* __restrict__ kT,
                                                 ushort* __restrict__ vT,
                                                 const float* __restrict__ sint,
                                                 const float* __restrict__ cost) {
  __attribute__((aligned(16))) __shared__ char smem[34816];
  ushort* As = (ushort*)smem;            // 2 bufs x 4096 ushorts
  ushort* Bs = (ushort*)(smem+16384);
  const int K = 1024;
  // B-resident XCD mapping: wg 0..3999
  int wg = blockIdx.x;
  int x = wg&7, i = wg>>3;               // i 0..499
  int nloc = i&3, mt = i>>2;             // mt 0..124
  int bm = mt*128, bn = (x*4+nloc)*128;
  int tid = threadIdx.x;
  int w = tid>>6, l = tid&63;
  int wm = (w>>1)*64, wn = (w&1)*64;
  int rsel = l&15, ko = (l>>4)*8;
  f32x4 acc[4][4];
  #pragma unroll
  for (int a2=0;a2<4;a2++)
    #pragma unroll
    for (int j=0;j<4;j++){ acc[a2][j][0]=0; acc[a2][j][1]=0; acc[a2][j][2]=0; acc[a2][j][3]=0; }
  const ushort* ap0 = A  + (size_t)(bm + w*32 + (l>>2))*K + (l&3)*8;
  const ushort* ap1 = ap0 + (size_t)16*K;
  const ushort* bp0 = BT + (size_t)(bn + w*32 + (l>>2))*K + (l&3)*8;
  const ushort* bp1 = bp0 + (size_t)16*K;
  {
    ushort* ab = As + w*1024; ushort* bb2 = Bs + w*1024;
    gload16(ap0, ab); gload16(ap1, ab+512);
    gload16(bp0, bb2); gload16(bp1, bb2+512);
  }
  int cur = 0;
  for (int kt=0; kt<K; kt+=32) {
    __syncthreads();
    if (kt+32 < K) {
      int nb = cur^1;
      ushort* ab = As + nb*4096 + w*1024; ushort* bb2 = Bs + nb*4096 + w*1024;
      gload16(ap0+kt+32, ab); gload16(ap1+kt+32, ab+512);
      gload16(bp0+kt+32, bb2); gload16(bp1+kt+32, bb2+512);
    }
    const ushort* Ac = As + cur*4096;
    const ushort* Bc = Bs + cur*4096;
    s16x8 af[4], bfr[4];
    #pragma unroll
    for (int mf=0;mf<4;mf++) af[mf]  = *(const s16x8*)&Ac[(wm+mf*16+rsel)*32 + ko];
    #pragma unroll
    for (int nf=0;nf<4;nf++) bfr[nf] = *(const s16x8*)&Bc[(wn+nf*16+rsel)*32 + ko];
    #pragma unroll
    for (int mf=0;mf<4;mf++)
      #pragma unroll
      for (int nf=0;nf<4;nf++)
        acc[mf][nf] = __builtin_amdgcn_mfma_f32_16x16x32_bf16(af[mf], bfr[nf], acc[mf][nf], 0,0,0);
    cur ^= 1;
  }
  // ---- LDS-staged epilogue ----
  int proj = bn>>10;            // block-uniform
  int bnp  = bn&1023;
  int hh   = bnp>>7;
  __syncthreads();              // staging done; reuse smem as Ct[128][136]
  ushort* Ct = (ushort*)smem;
  if (proj < 2) {
    float decay = logf(1.0f - exp2f(-5.0f-(float)hh));
    float ksc = 0.08838834764831845f;
    #pragma unroll
    for (int mf=0;mf<4;mf++) {
      #pragma unroll
      for (int r2=0;r2<4;r2++) {
        int rowt = wm+mf*16+(l>>4)*4+r2;
        int grow = bm+rowt;
        int t = grow - (grow/4000)*4000;
        int cch = t - (t/500)*500;
        float esc = (proj==0)? expf(decay*(float)cch) : expf(-decay*(float)cch)*ksc;
        const float* ctab = cost + (size_t)t*128;
        const float* stab = sint + (size_t)t*128;
        #pragma unroll
        for (int nf=0;nf<4;nf++) {
          int colt = wn+nf*16+(l&15);      // == d (bnp is 128-aligned)
          float vv = acc[mf][nf][r2];
          float cc = ctab[colt], ss = stab[colt];
          float ov = __shfl_xor(vv,1);
          float rot = ((l&1)==0)? (vv*cc-ov*ss) : (vv*cc+ov*ss);
          Ct[rowt*136+colt] = f2bf(rot*esc);
        }
      }
    }
  } else {
    #pragma unroll
    for (int mf=0;mf<4;mf++)
      #pragma unroll
      for (int nf=0;nf<4;nf++) {
        int colt = wn+nf*16+(l&15);
        #pragma unroll
        for (int r2=0;r2<4;r2++)
          Ct[(wm+mf*16+(l>>4)*4+r2)*136+colt] = f2bf(acc[mf][nf][r2]);
      }
  }
  __syncthreads();
  if (proj != 2) {
    ushort* dst = (proj==0)? qb : (proj==1)? kb : gb;
    int r = tid>>1, ch=(tid&1)*64;
    ushort* drow = dst + (size_t)(bm+r)*1024 + bnp + ch;
    #pragma unroll
    for (int j=0;j<8;j++) *(uint4*)(drow+j*8) = *(uint4*)&Ct[r*136+ch+j*8];
  }
  if (proj==1 || proj==2) {
    ushort* Tdst = (proj==1)? kT : vT;
    int dloc = tid>>1, rh=(tid&1)*64;
    #pragma unroll
    for (int j=0;j<8;j++) {
      int gr = bm + rh + j*8;
      int bb = gr/4000; int t0 = gr - bb*4000;
      int ch0 = t0/500; int c0 = t0 - ch0*500;
      if (c0 <= 492) {
        union{uint4 u; ushort s[8];} pk;
        #pragma unroll
        for (int ii=0;ii<8;ii++) pk.s[ii] = Ct[(rh+j*8+ii)*136 + dloc];
        *(uint4*)(Tdst + ((size_t)(bb*64+ch0*8+hh))*65536 + (size_t)dloc*512 + c0) = pk.u;
      } else {
        #pragma unroll
        for (int ii=0;ii<8;ii++) {
          int gri = gr+ii; int bbi=gri/4000; int ti=gri-bbi*4000; int chi=ti/500; int ci=ti-chi*500;
          Tdst[((size_t)(bbi*64+chi*8+hh))*65536 + (size_t)dloc*512 + ci] = Ct[(rh+j*8+ii)*136+dloc];
        }
      }
    }
  }
}

// ======== final GEMM: out[16000x1024] fp32 = opre @ WoT^T; XCD owns one Wo n-panel ========
__global__ __launch_bounds__(256) void gemm_out(const ushort* __restrict__ A,
                                                const ushort* __restrict__ BT,
                                                float* __restrict__ C) {
  __attribute__((aligned(16))) __shared__ char smem[34816];
  ushort* As = (ushort*)smem;
  ushort* Bs = (ushort*)(smem+16384);
  const int K = 1024;
  int wg = blockIdx.x;                   // 1000
  int x = wg&7, mt = wg>>3;              // mt 0..124
  int bm = mt*128, bn = x*128;
  int tid = threadIdx.x;
  int w = tid>>6, l = tid&63;
  int wm = (w>>1)*64, wn = (w&1)*64;
  int rsel = l&15, ko = (l>>4)*8;
  f32x4 acc[4][4];
  #pragma unroll
  for (int a2=0;a2<4;a2++)
    #pragma unroll
    for (int j=0;j<4;j++){ acc[a2][j][0]=0; acc[a2][j][1]=0; acc[a2][j][2]=0; acc[a2][j][3]=0; }
  const ushort* ap0 = A  + (size_t)(bm + w*32 + (l>>2))*K + (l&3)*8;
  const ushort* ap1 = ap0 + (size_t)16*K;
  const ushort* bp0 = BT + (size_t)(bn + w*32 + (l>>2))*K + (l&3)*8;
  const ushort* bp1 = bp0 + (size_t)16*K;
  {
    ushort* ab = As + w*1024; ushort* bb2 = Bs + w*1024;
    gload16(ap0, ab); gload16(ap1, ab+512);
    gload16(bp0, bb2); gload16(bp1, bb2+512);
  }
  int cur = 0;
  for (int kt=0; kt<K; kt+=32) {
    __syncthreads();
    if (kt+32 < K) {
      int nb = cur^1;
      ushort* ab = As + nb*4096 + w*1024; ushort* bb2 = Bs + nb*4096 + w*1024;
      gload16(ap0+kt+32, ab); gload16(ap1+kt+32, ab+512);
      gload16(bp0+kt+32, bb2); gload16(bp1+kt+32, bb2+512);
    }
    const ushort* Ac = As + cur*4096;
    const ushort* Bc = Bs + cur*4096;
    s16x8 af[4], bfr[4];
    #pragma unroll
    for (int mf=0;mf<4;mf++) af[mf]  = *(const s16x8*)&Ac[(wm+mf*16+rsel)*32 + ko];
    #pragma unroll
    for (int nf=0;nf<4;nf++) bfr[nf] = *(const s16x8*)&Bc[(wn+nf*16+rsel)*32 + ko];
    #pragma unroll
    for (int mf=0;mf<4;mf++)
      #pragma unroll
      for (int nf=0;nf<4;nf++)
        acc[mf][nf] = __builtin_amdgcn_mfma_f32_16x16x32_bf16(af[mf], bfr[nf], acc[mf][nf], 0,0,0);
    cur ^= 1;
  }
  __syncthreads();
  float* Cf = (float*)smem;  // [64][132]
  #pragma unroll
  for (int half=0; half<2; half++) {
    if ((w>>1)==half) {
      #pragma unroll
      for (int mf=0;mf<4;mf++)
        #pragma unroll
        for (int nf=0;nf<4;nf++)
          #pragma unroll
          for (int r2=0;r2<4;r2++)
            Cf[(mf*16+(l>>4)*4+r2)*132 + wn+nf*16+(l&15)] = acc[mf][nf][r2];
    }
    __syncthreads();
    {
      int r = tid>>2, cs=(tid&3)*32;
      float* drow = C + (size_t)(bm+half*64+r)*1024 + bn + cs;
      #pragma unroll
      for (int j=0;j<8;j++) *(float4*)(drow+j*4) = *(float4*)&Cf[r*132+cs+j*4];
    }
    __syncthreads();
  }
}

// ---- MFMA kv: kvp[bnh][dk][dv] = sum_c kT[dk][c]*vT[dv][c] (decay via prescale) ----
__global__ __launch_bounds__(256) void kv_mfma(const ushort* __restrict__ kT,
                                               const ushort* __restrict__ vT,
                                               float* __restrict__ kvp) {
  int bnh = blockIdx.x;
  __shared__ ushort sh2[16384];
  int tid=threadIdx.x;
  int wv=tid>>6, l=tid&63, g=l>>4, c16=l&15;
  int wr = wv>>1, wc = wv&1;
  int ri[4], ro[4];
  #pragma unroll
  for (int jj=0;jj<4;jj++){
    int i = wv*256 + jj*64 + l;
    ri[jj] = i>>3;
    ro[jj] = (((i&7)*16) ^ ((ri[jj]&7)<<4))>>1;
  }
  const ushort* kbase = kT + (size_t)bnh*65536;
  const ushort* vbase = vT + (size_t)bnh*65536;
  f32x4 acc[4][4];
  #pragma unroll
  for (int i=0;i<4;i++)
    #pragma unroll
    for (int j=0;j<4;j++){ acc[i][j][0]=0; acc[i][j][1]=0; acc[i][j][2]=0; acc[i][j][3]=0; }
  for (int ctep=0; ctep<8; ctep++) {
    int cb = ctep*64;
    __syncthreads();
    #pragma unroll
    for (int jj=0;jj<4;jj++){
      gload16(kbase + (size_t)ri[jj]*512 + cb + ro[jj], (ushort*)((char*)sh2 + wv*4096 + jj*1024));
      gload16(vbase + (size_t)ri[jj]*512 + cb + ro[jj], (ushort*)((char*)sh2 + 16384 + wv*4096 + jj*1024));
    }
    __syncthreads();
    if (ctep==7) {
      for (int z=tid; z<128*12; z+=256) {
        int r = z/12, j = 52 + (z - (z/12)*12);
        *(ushort*)((char*)sh2 + 16384 + r*128 + ((j*2) ^ ((r&7)<<4))) = 0;
      }
      __syncthreads();
    }
    #pragma unroll
    for (int kc=0;kc<2;kc++) {
      s16x8 af[4], bf2[4];
      #pragma unroll
      for (int mf=0;mf<4;mf++){
        int row = wr*64+mf*16+c16;
        af[mf] = *(const s16x8*)((const char*)sh2 + row*128 + ((((kc*32+g*8)*2)) ^ ((row&7)<<4)));
      }
      #pragma unroll
      for (int nf=0;nf<4;nf++){
        int row = wc*64+nf*16+c16;
        bf2[nf] = *(const s16x8*)((const char*)sh2 + 16384 + row*128 + ((((kc*32+g*8)*2)) ^ ((row&7)<<4)));
      }
      #pragma unroll
      for (int mf=0;mf<4;mf++)
        #pragma unroll
        for (int nf=0;nf<4;nf++)
          acc[mf][nf] = __builtin_amdgcn_mfma_f32_16x16x32_bf16(af[mf], bf2[nf], acc[mf][nf], 0,0,0);
    }
  }
  float* outp = kvp + (size_t)bnh*16384;
  #pragma unroll
  for (int mf=0;mf<4;mf++)
    #pragma unroll
    for (int nf=0;nf<4;nf++)
      #pragma unroll
      for (int reg=0;reg<4;reg++)
        outp[(size_t)(wr*64+mf*16+g*4+reg)*128 + wc*64+nf*16+c16] = acc[mf][nf][reg];
}

// ------- scan: st = st*cd + cst*kv_i ; kvrecT bf16 [dv][dk] -------
__global__ __launch_bounds__(256) void scan_kernel(const float* __restrict__ kvp,
                                                   ushort* __restrict__ kvrecT,
                                                   float* __restrict__ crosssc) {
  int bh = blockIdx.x;
  int b = bh>>3, h = bh&7;
  float Dh = 1.0f - exp2f(-5.0f-(float)h);
  float decay = logf(Dh);
  float cd = expf(decay*500.0f);
  float ls = (1.0f - expf(decay*500.0f))/(1.0f-Dh);
  float cst = expf(decay*499.0f)/ls;
  int tid=threadIdx.x;
  int vcol = tid&127, khalf = tid>>7;
  float st[64];
  #pragma unroll
  for (int i=0;i<64;i++) st[i]=0;
  float scale = 1.0f;
  __shared__ float colpart[2][128];
  __shared__ float sred[2];
  for (int n=0;n<8;n++) {
    int bnh = (b*8+n)*8+h;
    const float* src = kvp + (size_t)bnh*16384;
    ushort* rec = kvrecT + (size_t)bnh*16384;
    float inv = 1.0f/scale;
    float cs = 0;
    #pragma unroll
    for (int i=0;i<64;i++) {
      int kk = khalf*64+i;
      rec[(size_t)vcol*128+kk] = f2bf(st[i]*inv);
      st[i] = st[i]*cd + cst*src[(size_t)kk*128+vcol];
      cs += fabsf(st[i]);
    }
    if (tid==0) crosssc[bnh] = scale;
    colpart[khalf][vcol] = cs;
    __syncthreads();
    if (tid<128) colpart[0][tid] += colpart[1][tid];
    __syncthreads();
    float m = (tid<128)? colpart[0][tid] : 0.0f;
    #pragma unroll
    for (int o=32;o;o>>=1) m = fmaxf(m,__shfl_xor(m,o));
    if (tid<128 && (tid&63)==0) sred[tid>>6]=m;
    __syncthreads();
    scale = fmaxf(fmaxf(sred[0],sred[1]),1.0f);
    __syncthreads();
  }
}

// ---- retention core, XCD-grouped grid ----
__global__ __launch_bounds__(256,4) void iout_mfma(const ushort* __restrict__ qr,
                                                   const ushort* __restrict__ kr,
                                                   const ushort* __restrict__ vT,
                                                   const ushort* __restrict__ kvrecT,
                                                   const float* __restrict__ crosssc,
                                                   const ushort* __restrict__ gbuf,
                                                   ushort* __restrict__ opre) {
  int ib = blockIdx.x;
  int x = ib&7, u = ib>>3;
  int rt = u&7;
  int bnh = x*32 + (u>>3);
  int h = bnh&7, n=(bnh>>3)&7, b=bnh>>6;
  size_t base = (size_t)(b*4000+n*500)*1024 + h*128;
  float Dh = 1.0f - exp2f(-5.0f-(float)h);
  float decay = logf(Dh);
  __shared__ ushort sh[20480];
  char* shb = (char*)sh;
  int tid = threadIdx.x;
  int wv = tid>>6, l = tid&63;
  int g = l>>4, c16 = l&15;
  int r_base = rt*64 + wv*16 + g*4;

  int qrow = rt*64 + wv*16 + c16; if (qrow>499) qrow=499;
  s16x8 aq[4];
  #pragma unroll
  for (int kc=0;kc<4;kc++)
    aq[kc] = *(const s16x8*)(qr + base + (size_t)qrow*1024 + kc*32 + g*8);

  int ktrow[4], ktofs[4], vtrow[4], vtofs[4];
  #pragma unroll
  for (int jj=0;jj<4;jj++){
    int i = wv*256 + jj*64 + l;
    int r_ = i>>4;  ktrow[jj]=r_;  ktofs[jj] = (((i&15)*16) ^ ((r_&7)<<4))>>1;
    int r2_ = i>>3; vtrow[jj]=r2_; vtofs[jj] = (((i&7)*16) ^ ((r2_&7)<<4))>>1;
  }
  const ushort* vTb = vT + (size_t)bnh*65536;

  f32x4 pv[8], cc[8];
  #pragma unroll
  for (int i=0;i<8;i++){
    #pragma unroll
    for (int j=0;j<4;j++){ pv[i][j]=0.0f; cc[i][j]=0.0f; }
  }
  float rowsum[4] = {0,0,0,0};

  for (int et=0; et<=rt; et++) {
    __syncthreads();
    #pragma unroll
    for (int jj=0;jj<4;jj++){
      int gr = et*64 + ktrow[jj]; if (gr>499) gr=499;
      gload16(kr + base + (size_t)gr*1024 + ktofs[jj], (ushort*)(shb + wv*4096 + jj*1024));
      gload16(vTb + (size_t)vtrow[jj]*512 + et*64 + vtofs[jj], (ushort*)(shb + 16384 + wv*4096 + jj*1024));
    }
    __syncthreads();
    f32x4 S[4];
    #pragma unroll
    for (int i=0;i<4;i++){ S[i][0]=0; S[i][1]=0; S[i][2]=0; S[i][3]=0; }
    __builtin_amdgcn_s_setprio(1);
    #pragma unroll
    for (int kc=0;kc<4;kc++) {
      #pragma unroll
      for (int ni=0;ni<4;ni++) {
        int krow = ni*16+c16;
        s16x8 bf = *(const s16x8*)(shb + krow*256 + ((((kc*32+g*8)*2)) ^ ((krow&7)<<4)));
        S[ni] = __builtin_amdgcn_mfma_f32_16x16x32_bf16(aq[kc], bf, S[ni], 0,0,0);
      }
    }
    __builtin_amdgcn_s_setprio(0);
    bool diag = (et==rt);
    #pragma unroll
    for (int ni=0;ni<4;ni++) {
      int e_rel = et*64 + ni*16 + c16;
      #pragma unroll
      for (int reg=0;reg<4;reg++) {
        float p = S[ni][reg];
        if (diag && e_rel > r_base+reg) p = 0.0f;
        rowsum[reg] += fabsf(p);
        int prow = wv*16 + g*4 + reg;
        *(ushort*)(shb + 32768 + prow*128 + (((ni*16+c16)*2) ^ ((prow&7)<<4))) = f2bf(p);
      }
    }
    __builtin_amdgcn_s_setprio(1);
    #pragma unroll
    for (int kc=0;kc<2;kc++) {
      int prow = wv*16 + c16;
      s16x8 pa = *(const s16x8*)(shb + 32768 + prow*128 + ((((kc*32+g*8)*2)) ^ ((prow&7)<<4)));
      #pragma unroll
      for (int nf=0;nf<8;nf++) {
        int vrow = nf*16+c16;
        s16x8 vb = *(const s16x8*)(shb + 16384 + vrow*128 + ((((kc*32+g*8)*2)) ^ ((vrow&7)<<4)));
        pv[nf] = __builtin_amdgcn_mfma_f32_16x16x32_bf16(pa, vb, pv[nf], 0,0,0);
      }
    }
    __builtin_amdgcn_s_setprio(0);
  }
  #pragma unroll
  for (int reg=0;reg<4;reg++) {
    float s = rowsum[reg];
    s += __shfl_xor(s,1); s += __shfl_xor(s,2); s += __shfl_xor(s,4); s += __shfl_xor(s,8);
    rowsum[reg] = s;
  }
  __syncthreads();
  #pragma unroll
  for (int jj=0;jj<8;jj++){
    int i = wv*512 + jj*64 + l;
    int r_ = i>>4;
    int ofs = (((i&15)*16) ^ ((r_&7)<<4))>>1;
    gload16(kvrecT + (size_t)bnh*16384 + (size_t)r_*128 + ofs, (ushort*)(shb + wv*8192 + jj*1024));
  }
  __syncthreads();
  __builtin_amdgcn_s_setprio(1);
  #pragma unroll
  for (int kc=0;kc<4;kc++) {
    #pragma unroll
    for (int nf=0;nf<8;nf++) {
      int krow = nf*16+c16;
      s16x8 bb = *(const s16x8*)(shb + krow*256 + ((((kc*32+g*8)*2)) ^ ((krow&7)<<4)));
      cc[nf] = __builtin_amdgcn_mfma_f32_16x16x32_bf16(aq[kc], bb, cc[nf], 0,0,0);
    }
  }
  __builtin_amdgcn_s_setprio(0);
  float cs = crosssc[bnh];
  float lsum = (1.0f-expf(decay*500.0f))/(1.0f-Dh);
  float ed = expf(decay);
  #pragma unroll
  for (int reg=0;reg<4;reg++) {
    int rr = r_base + reg;
    if (rr < 500) {
      float rs = (1.0f-expf(decay*(float)(rr+1)))/(1.0f-Dh);
      float rsr = rsqrtf(rs);
      float is = fmaxf(1.0f, rowsum[reg]*rsr);
      float all = fmaxf(is, cs);
      float qid = ed*lsum*rsr;
      float fi = rsr/all;
      float fc = qid*(cs/all);
      float o[8]; float ssq = 0.0f;
      #pragma unroll
      for (int nf=0;nf<8;nf++){ o[nf] = pv[nf][reg]*fi + cc[nf][reg]*fc; ssq += o[nf]*o[nf]; }
      ssq += __shfl_xor(ssq,1); ssq += __shfl_xor(ssq,2); ssq += __shfl_xor(ssq,4); ssq += __shfl_xor(ssq,8);
      float rmss = rsqrtf(ssq*(1.0f/128.0f)+1e-6f);
      size_t rowoff = (size_t)(b*4000+n*500+rr)*1024 + h*128;
      #pragma unroll
      for (int nf=0;nf<8;nf++){
        float gv = bfu(gbuf[rowoff + nf*16 + c16]);
        float sg = gv/(1.0f+expf(-gv));
        opre[rowoff + nf*16 + c16] = f2bf(sg*o[nf]*rmss);
      }
    }
  }
}

extern "C" void kernel_launch(void* const* d_in, const int* in_sizes, int n_in,
                              void* d_out, int out_size, void* d_ws, size_t ws_size,
                              hipStream_t stream) {
  const float* x     = (const float*)d_in[0];
  const float* gamma = (const float*)d_in[1];
  const float* beta  = (const float*)d_in[2];
  const float* Wq    = (const float*)d_in[3];
  const float* Wk    = (const float*)d_in[4];
  const float* Wv    = (const float*)d_in[5];
  const float* Wg    = (const float*)d_in[6];
  const float* Wo    = (const float*)d_in[7];
  float* out = (float*)d_out;

  char* ws = (char*)d_ws;
  size_t off = 0;
  auto alloc = [&](size_t bytes)->void* { void* p = ws+off; off += (bytes+255)&~(size_t)255; return p; };
  const size_t BT1024 = (size_t)16000*1024;
  ushort* xln  = (ushort*)alloc(BT1024*2);   // reused: kvp (fp32, 16.8MB) then opre
  ushort* q    = (ushort*)alloc(BT1024*2);
  ushort* k    = (ushort*)alloc(BT1024*2);
  ushort* g    = (ushort*)alloc(BT1024*2);
  // NOTE: WqT..WgT MUST be contiguous (fused GEMM treats them as one [4096][1024])
  ushort* WqT  = (ushort*)alloc((size_t)1024*1024*2);
  ushort* WkT  = (ushort*)alloc((size_t)1024*1024*2);
  ushort* WvT  = (ushort*)alloc((size_t)1024*1024*2);
  ushort* WgT  = (ushort*)alloc((size_t)1024*1024*2);
  ushort* WoT  = (ushort*)alloc((size_t)1024*1024*2);
  float* sint  = (float*)alloc((size_t)4000*128*4);
  float* cost  = (float*)alloc((size_t)4000*128*4);
  ushort* kT   = (ushort*)alloc((size_t)256*65536*2);
  ushort* vT   = (ushort*)alloc((size_t)256*65536*2);
  ushort* kvrecT=(ushort*)alloc((size_t)256*16384*2);
  float* crosssc = (float*)alloc(256*4);
  (void)ws_size; (void)in_sizes; (void)n_in; (void)out_size;

  ln_kernel<<<16000,256,0,stream>>>(x,gamma,beta,xln);
  sincos_kernel<<<1000,256,0,stream>>>(sint,cost);
  dim3 tt(16,16,5);
  f2bf_t_all<<<tt,256,0,stream>>>(Wq,Wk,Wv,Wg,Wo, WqT,WkT,WvT,WgT,WoT);

  // one fused projection GEMM: BT = [WqT;WkT;WvT;WgT] (contiguous)
  gemm_proj<<<4000,256,0,stream>>>(xln, WqT, q, k, g, kT, vT, sint, cost);

  float* kvp = (float*)xln;   // xln dead after projections
  kv_mfma<<<256,256,0,stream>>>(kT,vT,kvp);
  scan_kernel<<<32,256,0,stream>>>(kvp,kvrecT,crosssc);

  ushort* opre = xln;         // kvp dead after scan
  iout_mfma<<<2048,256,0,stream>>>(q,k,vT,kvrecT,crosssc,g,opre);

  gemm_out<<<1000,256,0,stream>>>(opre,WoT,out);
}

// Round 12
// 429.621 us; speedup vs baseline: 1.2490x; 1.0404x over previous
//
#include <hip/hip_runtime.h>
#include <hip/hip_bf16.h>

// B=4, T=4000, D=1024, H=8, DK=128, CHUNK=500, N=T/CHUNK=8
// I/O fp32; internal bf16 with decay prescaled into q/k; fp32 accum.

typedef __attribute__((ext_vector_type(4))) float f32x4;
typedef __attribute__((ext_vector_type(8))) short s16x8;

#define DEV static __device__ __forceinline__

DEV float bfu(ushort u){ union{uint i; float f;} x; x.i=((uint)u)<<16; return x.f; }
DEV ushort f2bf(float f){ union{float f; uint u;} x; x.f=f; uint r = x.u + 0x7fffu + ((x.u>>16)&1u); return (ushort)(r>>16); }
DEV uint pack2(float lo, float hi){ return ((uint)f2bf(hi)<<16) | (uint)f2bf(lo); }

DEV void gload16(const ushort* g, ushort* l) {
  __builtin_amdgcn_global_load_lds((const __attribute__((address_space(1))) void*)g,
                                   (__attribute__((address_space(3))) void*)l, 16, 0, 0);
}

// ---------------- fp32 W[K][N] -> bf16 W^T[N][K], all 5 weights in one launch ----------------
__global__ __launch_bounds__(256) void f2bf_t_all(const float* __restrict__ s0, const float* __restrict__ s1,
                                                  const float* __restrict__ s2, const float* __restrict__ s3,
                                                  const float* __restrict__ s4,
                                                  ushort* __restrict__ d0, ushort* __restrict__ d1,
                                                  ushort* __restrict__ d2, ushort* __restrict__ d3,
                                                  ushort* __restrict__ d4) {
  const float* src; ushort* dst;
  switch (blockIdx.z) {
    case 0: src=s0; dst=d0; break;
    case 1: src=s1; dst=d1; break;
    case 2: src=s2; dst=d2; break;
    case 3: src=s3; dst=d3; break;
    default: src=s4; dst=d4; break;
  }
  __shared__ ushort t[64][72];
  int kt = blockIdx.x*64, nt = blockIdx.y*64;
  int tid = threadIdx.x;
  int r = tid>>2, c0 = (tid&3)*16;
  const float* s = src + (size_t)(kt+r)*1024 + nt + c0;
  #pragma unroll
  for (int j=0;j<16;j+=4) {
    float4 vv = *(const float4*)(s+j);
    t[r][c0+j]=f2bf(vv.x); t[r][c0+j+1]=f2bf(vv.y); t[r][c0+j+2]=f2bf(vv.z); t[r][c0+j+3]=f2bf(vv.w);
  }
  __syncthreads();
  union { uint4 u4[2]; ushort s16[16]; } tmp;
  #pragma unroll
  for (int j=0;j<16;j++) tmp.s16[j] = t[c0+j][r];
  ushort* d = dst + (size_t)(nt+r)*1024 + kt + c0;
  *(uint4*)(d)   = tmp.u4[0];
  *(uint4*)(d+8) = tmp.u4[1];
}

// ---------------- LayerNorm ----------------
__global__ __launch_bounds__(256) void ln_kernel(const float* __restrict__ x,
                                                 const float* __restrict__ gamma,
                                                 const float* __restrict__ beta,
                                                 ushort* __restrict__ xo) {
  int row = blockIdx.x;
  int tid = threadIdx.x;
  const float* xr = x + (size_t)row*1024;
  float4 u = ((const float4*)xr)[tid];
  float s = u.x+u.y+u.z+u.w;
  float sq = u.x*u.x+u.y*u.y+u.z*u.z+u.w*u.w;
  #pragma unroll
  for (int o=32;o;o>>=1){ s += __shfl_xor(s,o); sq += __shfl_xor(sq,o); }
  __shared__ float red[8];
  int wv=tid>>6, ln=tid&63;
  if (ln==0){ red[wv]=s; red[4+wv]=sq; }
  __syncthreads();
  s = red[0]+red[1]+red[2]+red[3];
  sq = red[4]+red[5]+red[6]+red[7];
  float mu = s*(1.0f/1024.0f);
  float var = sq*(1.0f/1024.0f)-mu*mu;
  float inv = rsqrtf(var+1e-5f);
  float4 gg = ((const float4*)gamma)[tid];
  float4 bb = ((const float4*)beta)[tid];
  float o0=(u.x-mu)*inv*gg.x+bb.x;
  float o1=(u.y-mu)*inv*gg.y+bb.y;
  float o2=(u.z-mu)*inv*gg.z+bb.z;
  float o3=(u.w-mu)*inv*gg.w+bb.w;
  uint2 w; w.x=pack2(o0,o1); w.y=pack2(o2,o3);
  ((uint2*)(xo+(size_t)row*1024))[tid]=w;
}

// ---------------- sin/cos tables [4000][128] fp32 ----------------
__global__ __launch_bounds__(256) void sincos_kernel(float* __restrict__ sint, float* __restrict__ cost) {
  int idx = blockIdx.x*256+threadIdx.x;
  if (idx >= 4000*64) return;
  int t = idx>>6, i = idx&63;
  float ang = expf(-9.210340371976184f * (float)i * (1.0f/63.0f));
  float a = (float)t * ang;
  float sv = sinf(a), cv = cosf(a);
  sint[(size_t)t*128+2*i] = sv; sint[(size_t)t*128+2*i+1] = sv;
  cost[(size_t)t*128+2*i] = cv; cost[(size_t)t*128+2*i+1] = cv;
}

// ======== fused projection GEMM: A[16000x1024] @ BT[4096x1024]^T, 4 outputs ========
// 128x128 tile, 256 thr + BALANCED B-resident XCD mapping:
// XCD x owns n-panels {x, x+8, x+16, x+24} (one per projection, 1MB L2-resident);
// 4 consecutive blocks share an A m-panel; every XCD runs the same epilogue mix.
__global__ __launch_bounds__(256) void gemm_proj(const ushort* __restrict__ A,
                                                 const ushort* __restrict__ BT,
                                                 ushort* __restrict__ qb,
                                                 ushort* __restrict__ kb,
                                                 ushort* __restrict__ gb,
                                                 ushort* __restrict__ kT,
                                                 ushort* __restrict__ vT,
                                                 const float* __restrict__ sint,
                                                 const float* __restrict__ cost) {
  __attribute__((aligned(16))) __shared__ char smem[34816];
  ushort* As = (ushort*)smem;            // 2 bufs x 4096 ushorts
  ushort* Bs = (ushort*)(smem+16384);
  const int K = 1024;
  // balanced B-resident XCD mapping: wg 0..3999
  int wg = blockIdx.x;
  int x = wg&7, i = wg>>3;               // i 0..499
  int nloc = i&3, mt = i>>2;             // mt 0..124
  int bm = mt*128, bn = (x + 8*nloc)*128;  // proj = nloc (block-uniform), head = x
  int tid = threadIdx.x;
  int w = tid>>6, l = tid&63;
  int wm = (w>>1)*64, wn = (w&1)*64;
  int rsel = l&15, ko = (l>>4)*8;
  f32x4 acc[4][4];
  #pragma unroll
  for (int a2=0;a2<4;a2++)
    #pragma unroll
    for (int j=0;j<4;j++){ acc[a2][j][0]=0; acc[a2][j][1]=0; acc[a2][j][2]=0; acc[a2][j][3]=0; }
  const ushort* ap0 = A  + (size_t)(bm + w*32 + (l>>2))*K + (l&3)*8;
  const ushort* ap1 = ap0 + (size_t)16*K;
  const ushort* bp0 = BT + (size_t)(bn + w*32 + (l>>2))*K + (l&3)*8;
  const ushort* bp1 = bp0 + (size_t)16*K;
  {
    ushort* ab = As + w*1024; ushort* bb2 = Bs + w*1024;
    gload16(ap0, ab); gload16(ap1, ab+512);
    gload16(bp0, bb2); gload16(bp1, bb2+512);
  }
  int cur = 0;
  for (int kt=0; kt<K; kt+=32) {
    __syncthreads();
    if (kt+32 < K) {
      int nb = cur^1;
      ushort* ab = As + nb*4096 + w*1024; ushort* bb2 = Bs + nb*4096 + w*1024;
      gload16(ap0+kt+32, ab); gload16(ap1+kt+32, ab+512);
      gload16(bp0+kt+32, bb2); gload16(bp1+kt+32, bb2+512);
    }
    const ushort* Ac = As + cur*4096;
    const ushort* Bc = Bs + cur*4096;
    s16x8 af[4], bfr[4];
    #pragma unroll
    for (int mf=0;mf<4;mf++) af[mf]  = *(const s16x8*)&Ac[(wm+mf*16+rsel)*32 + ko];
    #pragma unroll
    for (int nf=0;nf<4;nf++) bfr[nf] = *(const s16x8*)&Bc[(wn+nf*16+rsel)*32 + ko];
    #pragma unroll
    for (int mf=0;mf<4;mf++)
      #pragma unroll
      for (int nf=0;nf<4;nf++)
        acc[mf][nf] = __builtin_amdgcn_mfma_f32_16x16x32_bf16(af[mf], bfr[nf], acc[mf][nf], 0,0,0);
    cur ^= 1;
  }
  // ---- LDS-staged epilogue ----
  int proj = bn>>10;            // == nloc, block-uniform
  int bnp  = bn&1023;
  int hh   = bnp>>7;            // == x
  __syncthreads();              // staging done; reuse smem as Ct[128][136]
  ushort* Ct = (ushort*)smem;
  if (proj < 2) {
    float decay = logf(1.0f - exp2f(-5.0f-(float)hh));
    float ksc = 0.08838834764831845f;
    #pragma unroll
    for (int mf=0;mf<4;mf++) {
      #pragma unroll
      for (int r2=0;r2<4;r2++) {
        int rowt = wm+mf*16+(l>>4)*4+r2;
        int grow = bm+rowt;
        int t = grow - (grow/4000)*4000;
        int cch = t - (t/500)*500;
        float esc = (proj==0)? expf(decay*(float)cch) : expf(-decay*(float)cch)*ksc;
        const float* ctab = cost + (size_t)t*128;
        const float* stab = sint + (size_t)t*128;
        #pragma unroll
        for (int nf=0;nf<4;nf++) {
          int colt = wn+nf*16+(l&15);      // == d (bnp is 128-aligned)
          float vv = acc[mf][nf][r2];
          float cc = ctab[colt], ss = stab[colt];
          float ov = __shfl_xor(vv,1);
          float rot = ((l&1)==0)? (vv*cc-ov*ss) : (vv*cc+ov*ss);
          Ct[rowt*136+colt] = f2bf(rot*esc);
        }
      }
    }
  } else {
    #pragma unroll
    for (int mf=0;mf<4;mf++)
      #pragma unroll
      for (int nf=0;nf<4;nf++) {
        int colt = wn+nf*16+(l&15);
        #pragma unroll
        for (int r2=0;r2<4;r2++)
          Ct[(wm+mf*16+(l>>4)*4+r2)*136+colt] = f2bf(acc[mf][nf][r2]);
      }
  }
  __syncthreads();
  if (proj != 2) {
    ushort* dst = (proj==0)? qb : (proj==1)? kb : gb;
    int r = tid>>1, ch=(tid&1)*64;
    ushort* drow = dst + (size_t)(bm+r)*1024 + bnp + ch;
    #pragma unroll
    for (int j=0;j<8;j++) *(uint4*)(drow+j*8) = *(uint4*)&Ct[r*136+ch+j*8];
  }
  if (proj==1 || proj==2) {
    ushort* Tdst = (proj==1)? kT : vT;
    int dloc = tid>>1, rh=(tid&1)*64;
    #pragma unroll
    for (int j=0;j<8;j++) {
      int gr = bm + rh + j*8;
      int bb = gr/4000; int t0 = gr - bb*4000;
      int ch0 = t0/500; int c0 = t0 - ch0*500;
      if (c0 <= 492) {
        union{uint4 u; ushort s[8];} pk;
        #pragma unroll
        for (int ii=0;ii<8;ii++) pk.s[ii] = Ct[(rh+j*8+ii)*136 + dloc];
        *(uint4*)(Tdst + ((size_t)(bb*64+ch0*8+hh))*65536 + (size_t)dloc*512 + c0) = pk.u;
      } else {
        #pragma unroll
        for (int ii=0;ii<8;ii++) {
          int gri = gr+ii; int bbi=gri/4000; int ti=gri-bbi*4000; int chi=ti/500; int ci=ti-chi*500;
          Tdst[((size_t)(bbi*64+chi*8+hh))*65536 + (size_t)dloc*512 + ci] = Ct[(rh+j*8+ii)*136+dloc];
        }
      }
    }
  }
}

// ======== final GEMM: out[16000x1024] fp32 = opre @ WoT^T; XCD owns one Wo n-panel ========
__global__ __launch_bounds__(256) void gemm_out(const ushort* __restrict__ A,
                                                const ushort* __restrict__ BT,
                                                float* __restrict__ C) {
  __attribute__((aligned(16))) __shared__ char smem[34816];
  ushort* As = (ushort*)smem;
  ushort* Bs = (ushort*)(smem+16384);
  const int K = 1024;
  int wg = blockIdx.x;                   // 1000
  int x = wg&7, mt = wg>>3;              // mt 0..124
  int bm = mt*128, bn = x*128;
  int tid = threadIdx.x;
  int w = tid>>6, l = tid&63;
  int wm = (w>>1)*64, wn = (w&1)*64;
  int rsel = l&15, ko = (l>>4)*8;
  f32x4 acc[4][4];
  #pragma unroll
  for (int a2=0;a2<4;a2++)
    #pragma unroll
    for (int j=0;j<4;j++){ acc[a2][j][0]=0; acc[a2][j][1]=0; acc[a2][j][2]=0; acc[a2][j][3]=0; }
  const ushort* ap0 = A  + (size_t)(bm + w*32 + (l>>2))*K + (l&3)*8;
  const ushort* ap1 = ap0 + (size_t)16*K;
  const ushort* bp0 = BT + (size_t)(bn + w*32 + (l>>2))*K + (l&3)*8;
  const ushort* bp1 = bp0 + (size_t)16*K;
  {
    ushort* ab = As + w*1024; ushort* bb2 = Bs + w*1024;
    gload16(ap0, ab); gload16(ap1, ab+512);
    gload16(bp0, bb2); gload16(bp1, bb2+512);
  }
  int cur = 0;
  for (int kt=0; kt<K; kt+=32) {
    __syncthreads();
    if (kt+32 < K) {
      int nb = cur^1;
      ushort* ab = As + nb*4096 + w*1024; ushort* bb2 = Bs + nb*4096 + w*1024;
      gload16(ap0+kt+32, ab); gload16(ap1+kt+32, ab+512);
      gload16(bp0+kt+32, bb2); gload16(bp1+kt+32, bb2+512);
    }
    const ushort* Ac = As + cur*4096;
    const ushort* Bc = Bs + cur*4096;
    s16x8 af[4], bfr[4];
    #pragma unroll
    for (int mf=0;mf<4;mf++) af[mf]  = *(const s16x8*)&Ac[(wm+mf*16+rsel)*32 + ko];
    #pragma unroll
    for (int nf=0;nf<4;nf++) bfr[nf] = *(const s16x8*)&Bc[(wn+nf*16+rsel)*32 + ko];
    #pragma unroll
    for (int mf=0;mf<4;mf++)
      #pragma unroll
      for (int nf=0;nf<4;nf++)
        acc[mf][nf] = __builtin_amdgcn_mfma_f32_16x16x32_bf16(af[mf], bfr[nf], acc[mf][nf], 0,0,0);
    cur ^= 1;
  }
  __syncthreads();
  float* Cf = (float*)smem;  // [64][132]
  #pragma unroll
  for (int half=0; half<2; half++) {
    if ((w>>1)==half) {
      #pragma unroll
      for (int mf=0;mf<4;mf++)
        #pragma unroll
        for (int nf=0;nf<4;nf++)
          #pragma unroll
          for (int r2=0;r2<4;r2++)
            Cf[(mf*16+(l>>4)*4+r2)*132 + wn+nf*16+(l&15)] = acc[mf][nf][r2];
    }
    __syncthreads();
    {
      int r = tid>>2, cs=(tid&3)*32;
      float* drow = C + (size_t)(bm+half*64+r)*1024 + bn + cs;
      #pragma unroll
      for (int j=0;j<8;j++) *(float4*)(drow+j*4) = *(float4*)&Cf[r*132+cs+j*4];
    }
    __syncthreads();
  }
}

// ---- MFMA kv: kvp[bnh][dk][dv] = sum_c kT[dk][c]*vT[dv][c] (decay via prescale) ----
__global__ __launch_bounds__(256) void kv_mfma(const ushort* __restrict__ kT,
                                               const ushort* __restrict__ vT,
                                               float* __restrict__ kvp) {
  int bnh = blockIdx.x;
  __shared__ ushort sh2[16384];
  int tid=threadIdx.x;
  int wv=tid>>6, l=tid&63, g=l>>4, c16=l&15;
  int wr = wv>>1, wc = wv&1;
  int ri[4], ro[4];
  #pragma unroll
  for (int jj=0;jj<4;jj++){
    int i = wv*256 + jj*64 + l;
    ri[jj] = i>>3;
    ro[jj] = (((i&7)*16) ^ ((ri[jj]&7)<<4))>>1;
  }
  const ushort* kbase = kT + (size_t)bnh*65536;
  const ushort* vbase = vT + (size_t)bnh*65536;
  f32x4 acc[4][4];
  #pragma unroll
  for (int i=0;i<4;i++)
    #pragma unroll
    for (int j=0;j<4;j++){ acc[i][j][0]=0; acc[i][j][1]=0; acc[i][j][2]=0; acc[i][j][3]=0; }
  for (int ctep=0; ctep<8; ctep++) {
    int cb = ctep*64;
    __syncthreads();
    #pragma unroll
    for (int jj=0;jj<4;jj++){
      gload16(kbase + (size_t)ri[jj]*512 + cb + ro[jj], (ushort*)((char*)sh2 + wv*4096 + jj*1024));
      gload16(vbase + (size_t)ri[jj]*512 + cb + ro[jj], (ushort*)((char*)sh2 + 16384 + wv*4096 + jj*1024));
    }
    __syncthreads();
    if (ctep==7) {
      for (int z=tid; z<128*12; z+=256) {
        int r = z/12, j = 52 + (z - (z/12)*12);
        *(ushort*)((char*)sh2 + 16384 + r*128 + ((j*2) ^ ((r&7)<<4))) = 0;
      }
      __syncthreads();
    }
    #pragma unroll
    for (int kc=0;kc<2;kc++) {
      s16x8 af[4], bf2[4];
      #pragma unroll
      for (int mf=0;mf<4;mf++){
        int row = wr*64+mf*16+c16;
        af[mf] = *(const s16x8*)((const char*)sh2 + row*128 + ((((kc*32+g*8)*2)) ^ ((row&7)<<4)));
      }
      #pragma unroll
      for (int nf=0;nf<4;nf++){
        int row = wc*64+nf*16+c16;
        bf2[nf] = *(const s16x8*)((const char*)sh2 + 16384 + row*128 + ((((kc*32+g*8)*2)) ^ ((row&7)<<4)));
      }
      #pragma unroll
      for (int mf=0;mf<4;mf++)
        #pragma unroll
        for (int nf=0;nf<4;nf++)
          acc[mf][nf] = __builtin_amdgcn_mfma_f32_16x16x32_bf16(af[mf], bf2[nf], acc[mf][nf], 0,0,0);
    }
  }
  float* outp = kvp + (size_t)bnh*16384;
  #pragma unroll
  for (int mf=0;mf<4;mf++)
    #pragma unroll
    for (int nf=0;nf<4;nf++)
      #pragma unroll
      for (int reg=0;reg<4;reg++)
        outp[(size_t)(wr*64+mf*16+g*4+reg)*128 + wc*64+nf*16+c16] = acc[mf][nf][reg];
}

// ------- scan: st = st*cd + cst*kv_i ; kvrecT bf16 [dv][dk] -------
__global__ __launch_bounds__(256) void scan_kernel(const float* __restrict__ kvp,
                                                   ushort* __restrict__ kvrecT,
                                                   float* __restrict__ crosssc) {
  int bh = blockIdx.x;
  int b = bh>>3, h = bh&7;
  float Dh = 1.0f - exp2f(-5.0f-(float)h);
  float decay = logf(Dh);
  float cd = expf(decay*500.0f);
  float ls = (1.0f - expf(decay*500.0f))/(1.0f-Dh);
  float cst = expf(decay*499.0f)/ls;
  int tid=threadIdx.x;
  int vcol = tid&127, khalf = tid>>7;
  float st[64];
  #pragma unroll
  for (int i=0;i<64;i++) st[i]=0;
  float scale = 1.0f;
  __shared__ float colpart[2][128];
  __shared__ float sred[2];
  for (int n=0;n<8;n++) {
    int bnh = (b*8+n)*8+h;
    const float* src = kvp + (size_t)bnh*16384;
    ushort* rec = kvrecT + (size_t)bnh*16384;
    float inv = 1.0f/scale;
    float cs = 0;
    #pragma unroll
    for (int i=0;i<64;i++) {
      int kk = khalf*64+i;
      rec[(size_t)vcol*128+kk] = f2bf(st[i]*inv);
      st[i] = st[i]*cd + cst*src[(size_t)kk*128+vcol];
      cs += fabsf(st[i]);
    }
    if (tid==0) crosssc[bnh] = scale;
    colpart[khalf][vcol] = cs;
    __syncthreads();
    if (tid<128) colpart[0][tid] += colpart[1][tid];
    __syncthreads();
    float m = (tid<128)? colpart[0][tid] : 0.0f;
    #pragma unroll
    for (int o=32;o;o>>=1) m = fmaxf(m,__shfl_xor(m,o));
    if (tid<128 && (tid&63)==0) sred[tid>>6]=m;
    __syncthreads();
    scale = fmaxf(fmaxf(sred[0],sred[1]),1.0f);
    __syncthreads();
  }
}

// ---- retention core, XCD-grouped grid ----
__global__ __launch_bounds__(256,4) void iout_mfma(const ushort* __restrict__ qr,
                                                   const ushort* __restrict__ kr,
                                                   const ushort* __restrict__ vT,
                                                   const ushort* __restrict__ kvrecT,
                                                   const float* __restrict__ crosssc,
                                                   const ushort* __restrict__ gbuf,
                                                   ushort* __restrict__ opre) {
  int ib = blockIdx.x;
  int x = ib&7, u = ib>>3;
  int rt = u&7;
  int bnh = x*32 + (u>>3);
  int h = bnh&7, n=(bnh>>3)&7, b=bnh>>6;
  size_t base = (size_t)(b*4000+n*500)*1024 + h*128;
  float Dh = 1.0f - exp2f(-5.0f-(float)h);
  float decay = logf(Dh);
  __shared__ ushort sh[20480];
  char* shb = (char*)sh;
  int tid = threadIdx.x;
  int wv = tid>>6, l = tid&63;
  int g = l>>4, c16 = l&15;
  int r_base = rt*64 + wv*16 + g*4;

  int qrow = rt*64 + wv*16 + c16; if (qrow>499) qrow=499;
  s16x8 aq[4];
  #pragma unroll
  for (int kc=0;kc<4;kc++)
    aq[kc] = *(const s16x8*)(qr + base + (size_t)qrow*1024 + kc*32 + g*8);

  int ktrow[4], ktofs[4], vtrow[4], vtofs[4];
  #pragma unroll
  for (int jj=0;jj<4;jj++){
    int i = wv*256 + jj*64 + l;
    int r_ = i>>4;  ktrow[jj]=r_;  ktofs[jj] = (((i&15)*16) ^ ((r_&7)<<4))>>1;
    int r2_ = i>>3; vtrow[jj]=r2_; vtofs[jj] = (((i&7)*16) ^ ((r2_&7)<<4))>>1;
  }
  const ushort* vTb = vT + (size_t)bnh*65536;

  f32x4 pv[8], cc[8];
  #pragma unroll
  for (int i=0;i<8;i++){
    #pragma unroll
    for (int j=0;j<4;j++){ pv[i][j]=0.0f; cc[i][j]=0.0f; }
  }
  float rowsum[4] = {0,0,0,0};

  for (int et=0; et<=rt; et++) {
    __syncthreads();
    #pragma unroll
    for (int jj=0;jj<4;jj++){
      int gr = et*64 + ktrow[jj]; if (gr>499) gr=499;
      gload16(kr + base + (size_t)gr*1024 + ktofs[jj], (ushort*)(shb + wv*4096 + jj*1024));
      gload16(vTb + (size_t)vtrow[jj]*512 + et*64 + vtofs[jj], (ushort*)(shb + 16384 + wv*4096 + jj*1024));
    }
    __syncthreads();
    f32x4 S[4];
    #pragma unroll
    for (int i=0;i<4;i++){ S[i][0]=0; S[i][1]=0; S[i][2]=0; S[i][3]=0; }
    __builtin_amdgcn_s_setprio(1);
    #pragma unroll
    for (int kc=0;kc<4;kc++) {
      #pragma unroll
      for (int ni=0;ni<4;ni++) {
        int krow = ni*16+c16;
        s16x8 bf = *(const s16x8*)(shb + krow*256 + ((((kc*32+g*8)*2)) ^ ((krow&7)<<4)));
        S[ni] = __builtin_amdgcn_mfma_f32_16x16x32_bf16(aq[kc], bf, S[ni], 0,0,0);
      }
    }
    __builtin_amdgcn_s_setprio(0);
    bool diag = (et==rt);
    #pragma unroll
    for (int ni=0;ni<4;ni++) {
      int e_rel = et*64 + ni*16 + c16;
      #pragma unroll
      for (int reg=0;reg<4;reg++) {
        float p = S[ni][reg];
        if (diag && e_rel > r_base+reg) p = 0.0f;
        rowsum[reg] += fabsf(p);
        int prow = wv*16 + g*4 + reg;
        *(ushort*)(shb + 32768 + prow*128 + (((ni*16+c16)*2) ^ ((prow&7)<<4))) = f2bf(p);
      }
    }
    __builtin_amdgcn_s_setprio(1);
    #pragma unroll
    for (int kc=0;kc<2;kc++) {
      int prow = wv*16 + c16;
      s16x8 pa = *(const s16x8*)(shb + 32768 + prow*128 + ((((kc*32+g*8)*2)) ^ ((prow&7)<<4)));
      #pragma unroll
      for (int nf=0;nf<8;nf++) {
        int vrow = nf*16+c16;
        s16x8 vb = *(const s16x8*)(shb + 16384 + vrow*128 + ((((kc*32+g*8)*2)) ^ ((vrow&7)<<4)));
        pv[nf] = __builtin_amdgcn_mfma_f32_16x16x32_bf16(pa, vb, pv[nf], 0,0,0);
      }
    }
    __builtin_amdgcn_s_setprio(0);
  }
  #pragma unroll
  for (int reg=0;reg<4;reg++) {
    float s = rowsum[reg];
    s += __shfl_xor(s,1); s += __shfl_xor(s,2); s += __shfl_xor(s,4); s += __shfl_xor(s,8);
    rowsum[reg] = s;
  }
  __syncthreads();
  #pragma unroll
  for (int jj=0;jj<8;jj++){
    int i = wv*512 + jj*64 + l;
    int r_ = i>>4;
    int ofs = (((i&15)*16) ^ ((r_&7)<<4))>>1;
    gload16(kvrecT + (size_t)bnh*16384 + (size_t)r_*128 + ofs, (ushort*)(shb + wv*8192 + jj*1024));
  }
  __syncthreads();
  __builtin_amdgcn_s_setprio(1);
  #pragma unroll
  for (int kc=0;kc<4;kc++) {
    #pragma unroll
    for (int nf=0;nf<8;nf++) {
      int krow = nf*16+c16;
      s16x8 bb = *(const s16x8*)(shb + krow*256 + ((((kc*32+g*8)*2)) ^ ((krow&7)<<4)));
      cc[nf] = __builtin_amdgcn_mfma_f32_16x16x32_bf16(aq[kc], bb, cc[nf], 0,0,0);
    }
  }
  __builtin_amdgcn_s_setprio(0);
  float cs = crosssc[bnh];
  float lsum = (1.0f-expf(decay*500.0f))/(1.0f-Dh);
  float ed = expf(decay);
  #pragma unroll
  for (int reg=0;reg<4;reg++) {
    int rr = r_base + reg;
    if (rr < 500) {
      float rs = (1.0f-expf(decay*(float)(rr+1)))/(1.0f-Dh);
      float rsr = rsqrtf(rs);
      float is = fmaxf(1.0f, rowsum[reg]*rsr);
      float all = fmaxf(is, cs);
      float qid = ed*lsum*rsr;
      float fi = rsr/all;
      float fc = qid*(cs/all);
      float o[8]; float ssq = 0.0f;
      #pragma unroll
      for (int nf=0;nf<8;nf++){ o[nf] = pv[nf][reg]*fi + cc[nf][reg]*fc; ssq += o[nf]*o[nf]; }
      ssq += __shfl_xor(ssq,1); ssq += __shfl_xor(ssq,2); ssq += __shfl_xor(ssq,4); ssq += __shfl_xor(ssq,8);
      float rmss = rsqrtf(ssq*(1.0f/128.0f)+1e-6f);
      size_t rowoff = (size_t)(b*4000+n*500+rr)*1024 + h*128;
      #pragma unroll
      for (int nf=0;nf<8;nf++){
        float gv = bfu(gbuf[rowoff + nf*16 + c16]);
        float sg = gv/(1.0f+expf(-gv));
        opre[rowoff + nf*16 + c16] = f2bf(sg*o[nf]*rmss);
      }
    }
  }
}

extern "C" void kernel_launch(void* const* d_in, const int* in_sizes, int n_in,
                              void* d_out, int out_size, void* d_ws, size_t ws_size,
                              hipStream_t stream) {
  const float* x     = (const float*)d_in[0];
  const float* gamma = (const float*)d_in[1];
  const float* beta  = (const float*)d_in[2];
  const float* Wq    = (const float*)d_in[3];
  const float* Wk    = (const float*)d_in[4];
  const float* Wv    = (const float*)d_in[5];
  const float* Wg    = (const float*)d_in[6];
  const float* Wo    = (const float*)d_in[7];
  float* out = (float*)d_out;

  char* ws = (char*)d_ws;
  size_t off = 0;
  auto alloc = [&](size_t bytes)->void* { void* p = ws+off; off += (bytes+255)&~(size_t)255; return p; };
  const size_t BT1024 = (size_t)16000*1024;
  ushort* xln  = (ushort*)alloc(BT1024*2);   // reused: kvp (fp32, 16.8MB) then opre
  ushort* q    = (ushort*)alloc(BT1024*2);
  ushort* k    = (ushort*)alloc(BT1024*2);
  ushort* g    = (ushort*)alloc(BT1024*2);
  // NOTE: WqT..WgT MUST be contiguous (fused GEMM treats them as one [4096][1024])
  ushort* WqT  = (ushort*)alloc((size_t)1024*1024*2);
  ushort* WkT  = (ushort*)alloc((size_t)1024*1024*2);
  ushort* WvT  = (ushort*)alloc((size_t)1024*1024*2);
  ushort* WgT  = (ushort*)alloc((size_t)1024*1024*2);
  ushort* WoT  = (ushort*)alloc((size_t)1024*1024*2);
  float* sint  = (float*)alloc((size_t)4000*128*4);
  float* cost  = (float*)alloc((size_t)4000*128*4);
  ushort* kT   = (ushort*)alloc((size_t)256*65536*2);
  ushort* vT   = (ushort*)alloc((size_t)256*65536*2);
  ushort* kvrecT=(ushort*)alloc((size_t)256*16384*2);
  float* crosssc = (float*)alloc(256*4);
  (void)ws_size; (void)in_sizes; (void)n_in; (void)out_size;

  ln_kernel<<<16000,256,0,stream>>>(x,gamma,beta,xln);
  sincos_kernel<<<1000,256,0,stream>>>(sint,cost);
  dim3 tt(16,16,5);
  f2bf_t_all<<<tt,256,0,stream>>>(Wq,Wk,Wv,Wg,Wo, WqT,WkT,WvT,WgT,WoT);

  // one fused projection GEMM: BT = [WqT;WkT;WvT;WgT] (contiguous)
  gemm_proj<<<4000,256,0,stream>>>(xln, WqT, q, k, g, kT, vT, sint, cost);

  float* kvp = (float*)xln;   // xln dead after projections
  kv_mfma<<<256,256,0,stream>>>(kT,vT,kvp);
  scan_kernel<<<32,256,0,stream>>>(kvp,kvrecT,crosssc);

  ushort* opre = xln;         // kvp dead after scan
  iout_mfma<<<2048,256,0,stream>>>(q,k,vT,kvrecT,crosssc,g,opre);

  gemm_out<<<1000,256,0,stream>>>(opre,WoT,out);
}

// Round 13
// 392.830 us; speedup vs baseline: 1.3660x; 1.0937x over previous
//
#include <hip/hip_runtime.h>
#include <hip/hip_bf16.h>

// B=4, T=4000, D=1024, H=8, DK=128, CHUNK=500, N=T/CHUNK=8
// I/O fp32; internal bf16 with decay prescaled into q/k; fp32 accum.

typedef __attribute__((ext_vector_type(4))) float f32x4;
typedef __attribute__((ext_vector_type(8))) short s16x8;

#define DEV static __device__ __forceinline__

DEV float bfu(ushort u){ union{uint i; float f;} x; x.i=((uint)u)<<16; return x.f; }
DEV float bflo(uint w){ union{uint i; float f;} x; x.i=w<<16; return x.f; }
DEV float bfhi(uint w){ union{uint i; float f;} x; x.i=w&0xffff0000u; return x.f; }
DEV ushort f2bf(float f){ union{float f; uint u;} x; x.f=f; uint r = x.u + 0x7fffu + ((x.u>>16)&1u); return (ushort)(r>>16); }
DEV uint pack2(float lo, float hi){ return ((uint)f2bf(hi)<<16) | (uint)f2bf(lo); }

DEV void gload16(const ushort* g, ushort* l) {
  __builtin_amdgcn_global_load_lds((const __attribute__((address_space(1))) void*)g,
                                   (__attribute__((address_space(3))) void*)l, 16, 0, 0);
}

// ---------------- fp32 W[K][N] -> bf16 W^T[N][K], all 5 weights in one launch ----------------
__global__ __launch_bounds__(256) void f2bf_t_all(const float* __restrict__ s0, const float* __restrict__ s1,
                                                  const float* __restrict__ s2, const float* __restrict__ s3,
                                                  const float* __restrict__ s4,
                                                  ushort* __restrict__ d0, ushort* __restrict__ d1,
                                                  ushort* __restrict__ d2, ushort* __restrict__ d3,
                                                  ushort* __restrict__ d4) {
  const float* src; ushort* dst;
  switch (blockIdx.z) {
    case 0: src=s0; dst=d0; break;
    case 1: src=s1; dst=d1; break;
    case 2: src=s2; dst=d2; break;
    case 3: src=s3; dst=d3; break;
    default: src=s4; dst=d4; break;
  }
  __shared__ ushort t[64][72];
  int kt = blockIdx.x*64, nt = blockIdx.y*64;
  int tid = threadIdx.x;
  int r = tid>>2, c0 = (tid&3)*16;
  const float* s = src + (size_t)(kt+r)*1024 + nt + c0;
  #pragma unroll
  for (int j=0;j<16;j+=4) {
    float4 vv = *(const float4*)(s+j);
    t[r][c0+j]=f2bf(vv.x); t[r][c0+j+1]=f2bf(vv.y); t[r][c0+j+2]=f2bf(vv.z); t[r][c0+j+3]=f2bf(vv.w);
  }
  __syncthreads();
  union { uint4 u4[2]; ushort s16[16]; } tmp;
  #pragma unroll
  for (int j=0;j<16;j++) tmp.s16[j] = t[c0+j][r];
  ushort* d = dst + (size_t)(nt+r)*1024 + kt + c0;
  *(uint4*)(d)   = tmp.u4[0];
  *(uint4*)(d+8) = tmp.u4[1];
}

// ---------------- LayerNorm ----------------
__global__ __launch_bounds__(256) void ln_kernel(const float* __restrict__ x,
                                                 const float* __restrict__ gamma,
                                                 const float* __restrict__ beta,
                                                 ushort* __restrict__ xo) {
  int row = blockIdx.x;
  int tid = threadIdx.x;
  const float* xr = x + (size_t)row*1024;
  float4 u = ((const float4*)xr)[tid];
  float s = u.x+u.y+u.z+u.w;
  float sq = u.x*u.x+u.y*u.y+u.z*u.z+u.w*u.w;
  #pragma unroll
  for (int o=32;o;o>>=1){ s += __shfl_xor(s,o); sq += __shfl_xor(sq,o); }
  __shared__ float red[8];
  int wv=tid>>6, ln=tid&63;
  if (ln==0){ red[wv]=s; red[4+wv]=sq; }
  __syncthreads();
  s = red[0]+red[1]+red[2]+red[3];
  sq = red[4]+red[5]+red[6]+red[7];
  float mu = s*(1.0f/1024.0f);
  float var = sq*(1.0f/1024.0f)-mu*mu;
  float inv = rsqrtf(var+1e-5f);
  float4 gg = ((const float4*)gamma)[tid];
  float4 bb = ((const float4*)beta)[tid];
  float o0=(u.x-mu)*inv*gg.x+bb.x;
  float o1=(u.y-mu)*inv*gg.y+bb.y;
  float o2=(u.z-mu)*inv*gg.z+bb.z;
  float o3=(u.w-mu)*inv*gg.w+bb.w;
  uint2 w; w.x=pack2(o0,o1); w.y=pack2(o2,o3);
  ((uint2*)(xo+(size_t)row*1024))[tid]=w;
}

// ------- packed bf16 cos|sin table: cstab[t*128+d] = (sin<<16)|cos, 2MB total -------
__global__ __launch_bounds__(256) void sincos_kernel(uint* __restrict__ cstab) {
  int idx = blockIdx.x*256+threadIdx.x;
  if (idx >= 4000*64) return;
  int t = idx>>6, i = idx&63;
  float ang = expf(-9.210340371976184f * (float)i * (1.0f/63.0f));
  float a = (float)t * ang;
  float sv = sinf(a), cv = cosf(a);
  uint p = pack2(cv, sv);          // low = cos, high = sin
  cstab[(size_t)t*128+2*i]   = p;
  cstab[(size_t)t*128+2*i+1] = p;
}

// ======== fused projection GEMM: A[16000x1024] @ BT[4096x1024]^T, 4 outputs ========
// Round-9 supertile mapping (measured best): supers of 16 m-panels, n-outer/m-inner.
// proj 0: q rot+prescale  1: k rot+scale + kT  2: vT only  3: g plain. LDS-staged epilogues.
__global__ __launch_bounds__(256) void gemm_proj(const ushort* __restrict__ A,
                                                 const ushort* __restrict__ BT,
                                                 ushort* __restrict__ qb,
                                                 ushort* __restrict__ kb,
                                                 ushort* __restrict__ gb,
                                                 ushort* __restrict__ kT,
                                                 ushort* __restrict__ vT,
                                                 const uint* __restrict__ cstab) {
  __attribute__((aligned(16))) __shared__ char smem[34816];
  ushort* As = (ushort*)smem;            // 2 bufs x 4096 ushorts
  ushort* Bs = (ushort*)(smem+16384);
  const int K = 1024;
  // supertile decode: supers 0..6 = 16 m-panels (512 blocks), super 7 = 13 (416 blocks)
  int wg = blockIdx.x;
  int s, r9, sm;
  if (wg < 3584) { s = wg>>9; r9 = wg&511; sm = 16; }
  else           { s = 7;     r9 = wg-3584; sm = 13; }
  int nblk = r9 / sm;
  int mloc = r9 - nblk*sm;
  int bm = (s*16 + mloc)*128, bn = nblk*128;
  int tid = threadIdx.x;
  int w = tid>>6, l = tid&63;
  int wm = (w>>1)*64, wn = (w&1)*64;
  int rsel = l&15, ko = (l>>4)*8;
  f32x4 acc[4][4];
  #pragma unroll
  for (int a2=0;a2<4;a2++)
    #pragma unroll
    for (int j=0;j<4;j++){ acc[a2][j][0]=0; acc[a2][j][1]=0; acc[a2][j][2]=0; acc[a2][j][3]=0; }
  const ushort* ap0 = A  + (size_t)(bm + w*32 + (l>>2))*K + (l&3)*8;
  const ushort* ap1 = ap0 + (size_t)16*K;
  const ushort* bp0 = BT + (size_t)(bn + w*32 + (l>>2))*K + (l&3)*8;
  const ushort* bp1 = bp0 + (size_t)16*K;
  {
    ushort* ab = As + w*1024; ushort* bb2 = Bs + w*1024;
    gload16(ap0, ab); gload16(ap1, ab+512);
    gload16(bp0, bb2); gload16(bp1, bb2+512);
  }
  int cur = 0;
  for (int kt=0; kt<K; kt+=32) {
    __syncthreads();
    if (kt+32 < K) {
      int nb = cur^1;
      ushort* ab = As + nb*4096 + w*1024; ushort* bb2 = Bs + nb*4096 + w*1024;
      gload16(ap0+kt+32, ab); gload16(ap1+kt+32, ab+512);
      gload16(bp0+kt+32, bb2); gload16(bp1+kt+32, bb2+512);
    }
    const ushort* Ac = As + cur*4096;
    const ushort* Bc = Bs + cur*4096;
    s16x8 af[4], bfr[4];
    #pragma unroll
    for (int mf=0;mf<4;mf++) af[mf]  = *(const s16x8*)&Ac[(wm+mf*16+rsel)*32 + ko];
    #pragma unroll
    for (int nf=0;nf<4;nf++) bfr[nf] = *(const s16x8*)&Bc[(wn+nf*16+rsel)*32 + ko];
    #pragma unroll
    for (int mf=0;mf<4;mf++)
      #pragma unroll
      for (int nf=0;nf<4;nf++)
        acc[mf][nf] = __builtin_amdgcn_mfma_f32_16x16x32_bf16(af[mf], bfr[nf], acc[mf][nf], 0,0,0);
    cur ^= 1;
  }
  // ---- LDS-staged epilogue ----
  int proj = bn>>10;            // block-uniform
  int bnp  = bn&1023;
  int hh   = bnp>>7;
  __syncthreads();              // staging done; reuse smem as Ct[128][136]
  ushort* Ct = (ushort*)smem;
  if (proj < 2) {
    float decay = logf(1.0f - exp2f(-5.0f-(float)hh));
    float ksc = 0.08838834764831845f;
    #pragma unroll
    for (int mf=0;mf<4;mf++) {
      #pragma unroll
      for (int r2=0;r2<4;r2++) {
        int rowt = wm+mf*16+(l>>4)*4+r2;
        int grow = bm+rowt;
        int t = grow - (grow/4000)*4000;
        int cch = t - (t/500)*500;
        float esc = (proj==0)? expf(decay*(float)cch) : expf(-decay*(float)cch)*ksc;
        const uint* cst = cstab + (size_t)t*128;
        #pragma unroll
        for (int nf=0;nf<4;nf++) {
          int colt = wn+nf*16+(l&15);      // == d (bnp is 128-aligned)
          float vv = acc[mf][nf][r2];
          uint wcs = cst[colt];
          float cc = bflo(wcs), ss = bfhi(wcs);
          float ov = __shfl_xor(vv,1);
          float rot = ((l&1)==0)? (vv*cc-ov*ss) : (vv*cc+ov*ss);
          Ct[rowt*136+colt] = f2bf(rot*esc);
        }
      }
    }
  } else {
    #pragma unroll
    for (int mf=0;mf<4;mf++)
      #pragma unroll
      for (int nf=0;nf<4;nf++) {
        int colt = wn+nf*16+(l&15);
        #pragma unroll
        for (int r2=0;r2<4;r2++)
          Ct[(wm+mf*16+(l>>4)*4+r2)*136+colt] = f2bf(acc[mf][nf][r2]);
      }
  }
  __syncthreads();
  if (proj != 2) {
    ushort* dst = (proj==0)? qb : (proj==1)? kb : gb;
    int r = tid>>1, ch=(tid&1)*64;
    ushort* drow = dst + (size_t)(bm+r)*1024 + bnp + ch;
    #pragma unroll
    for (int j=0;j<8;j++) *(uint4*)(drow+j*8) = *(uint4*)&Ct[r*136+ch+j*8];
  }
  if (proj==1 || proj==2) {
    ushort* Tdst = (proj==1)? kT : vT;
    int dloc = tid>>1, rh=(tid&1)*64;
    #pragma unroll
    for (int j=0;j<8;j++) {
      int gr = bm + rh + j*8;
      int bb = gr/4000; int t0 = gr - bb*4000;
      int ch0 = t0/500; int c0 = t0 - ch0*500;
      if (c0 <= 492) {
        union{uint4 u; ushort s[8];} pk;
        #pragma unroll
        for (int ii=0;ii<8;ii++) pk.s[ii] = Ct[(rh+j*8+ii)*136 + dloc];
        *(uint4*)(Tdst + ((size_t)(bb*64+ch0*8+hh))*65536 + (size_t)dloc*512 + c0) = pk.u;
      } else {
        #pragma unroll
        for (int ii=0;ii<8;ii++) {
          int gri = gr+ii; int bbi=gri/4000; int ti=gri-bbi*4000; int chi=ti/500; int ci=ti-chi*500;
          Tdst[((size_t)(bbi*64+chi*8+hh))*65536 + (size_t)dloc*512 + ci] = Ct[(rh+j*8+ii)*136+dloc];
        }
      }
    }
  }
}

// ======== final GEMM: out[16000x1024] fp32 = opre @ WoT^T, round-9 supertile, LDS epilogue ========
__global__ __launch_bounds__(256) void gemm_out(const ushort* __restrict__ A,
                                                const ushort* __restrict__ BT,
                                                float* __restrict__ C) {
  __attribute__((aligned(16))) __shared__ char smem[34816];
  ushort* As = (ushort*)smem;
  ushort* Bs = (ushort*)(smem+16384);
  const int K = 1024;
  int wg = blockIdx.x;
  int s, r9, sm;
  if (wg < 896) { s = wg>>7; r9 = wg&127; sm = 16; }
  else          { s = 7;     r9 = wg-896; sm = 13; }
  int nblk = r9 / sm;
  int mloc = r9 - nblk*sm;
  int bm = (s*16 + mloc)*128, bn = nblk*128;
  int tid = threadIdx.x;
  int w = tid>>6, l = tid&63;
  int wm = (w>>1)*64, wn = (w&1)*64;
  int rsel = l&15, ko = (l>>4)*8;
  f32x4 acc[4][4];
  #pragma unroll
  for (int a2=0;a2<4;a2++)
    #pragma unroll
    for (int j=0;j<4;j++){ acc[a2][j][0]=0; acc[a2][j][1]=0; acc[a2][j][2]=0; acc[a2][j][3]=0; }
  const ushort* ap0 = A  + (size_t)(bm + w*32 + (l>>2))*K + (l&3)*8;
  const ushort* ap1 = ap0 + (size_t)16*K;
  const ushort* bp0 = BT + (size_t)(bn + w*32 + (l>>2))*K + (l&3)*8;
  const ushort* bp1 = bp0 + (size_t)16*K;
  {
    ushort* ab = As + w*1024; ushort* bb2 = Bs + w*1024;
    gload16(ap0, ab); gload16(ap1, ab+512);
    gload16(bp0, bb2); gload16(bp1, bb2+512);
  }
  int cur = 0;
  for (int kt=0; kt<K; kt+=32) {
    __syncthreads();
    if (kt+32 < K) {
      int nb = cur^1;
      ushort* ab = As + nb*4096 + w*1024; ushort* bb2 = Bs + nb*4096 + w*1024;
      gload16(ap0+kt+32, ab); gload16(ap1+kt+32, ab+512);
      gload16(bp0+kt+32, bb2); gload16(bp1+kt+32, bb2+512);
    }
    const ushort* Ac = As + cur*4096;
    const ushort* Bc = Bs + cur*4096;
    s16x8 af[4], bfr[4];
    #pragma unroll
    for (int mf=0;mf<4;mf++) af[mf]  = *(const s16x8*)&Ac[(wm+mf*16+rsel)*32 + ko];
    #pragma unroll
    for (int nf=0;nf<4;nf++) bfr[nf] = *(const s16x8*)&Bc[(wn+nf*16+rsel)*32 + ko];
    #pragma unroll
    for (int mf=0;mf<4;mf++)
      #pragma unroll
      for (int nf=0;nf<4;nf++)
        acc[mf][nf] = __builtin_amdgcn_mfma_f32_16x16x32_bf16(af[mf], bfr[nf], acc[mf][nf], 0,0,0);
    cur ^= 1;
  }
  __syncthreads();
  float* Cf = (float*)smem;  // [64][132]
  #pragma unroll
  for (int half=0; half<2; half++) {
    if ((w>>1)==half) {
      #pragma unroll
      for (int mf=0;mf<4;mf++)
        #pragma unroll
        for (int nf=0;nf<4;nf++)
          #pragma unroll
          for (int r2=0;r2<4;r2++)
            Cf[(mf*16+(l>>4)*4+r2)*132 + wn+nf*16+(l&15)] = acc[mf][nf][r2];
    }
    __syncthreads();
    {
      int r = tid>>2, cs=(tid&3)*32;
      float* drow = C + (size_t)(bm+half*64+r)*1024 + bn + cs;
      #pragma unroll
      for (int j=0;j<8;j++) *(float4*)(drow+j*4) = *(float4*)&Cf[r*132+cs+j*4];
    }
    __syncthreads();
  }
}

// ---- MFMA kv: kvp[bnh][dk][dv] = sum_c kT[dk][c]*vT[dv][c] (decay via prescale) ----
__global__ __launch_bounds__(256) void kv_mfma(const ushort* __restrict__ kT,
                                               const ushort* __restrict__ vT,
                                               float* __restrict__ kvp) {
  int bnh = blockIdx.x;
  __shared__ ushort sh2[16384];
  int tid=threadIdx.x;
  int wv=tid>>6, l=tid&63, g=l>>4, c16=l&15;
  int wr = wv>>1, wc = wv&1;
  int ri[4], ro[4];
  #pragma unroll
  for (int jj=0;jj<4;jj++){
    int i = wv*256 + jj*64 + l;
    ri[jj] = i>>3;
    ro[jj] = (((i&7)*16) ^ ((ri[jj]&7)<<4))>>1;
  }
  const ushort* kbase = kT + (size_t)bnh*65536;
  const ushort* vbase = vT + (size_t)bnh*65536;
  f32x4 acc[4][4];
  #pragma unroll
  for (int i=0;i<4;i++)
    #pragma unroll
    for (int j=0;j<4;j++){ acc[i][j][0]=0; acc[i][j][1]=0; acc[i][j][2]=0; acc[i][j][3]=0; }
  for (int ctep=0; ctep<8; ctep++) {
    int cb = ctep*64;
    __syncthreads();
    #pragma unroll
    for (int jj=0;jj<4;jj++){
      gload16(kbase + (size_t)ri[jj]*512 + cb + ro[jj], (ushort*)((char*)sh2 + wv*4096 + jj*1024));
      gload16(vbase + (size_t)ri[jj]*512 + cb + ro[jj], (ushort*)((char*)sh2 + 16384 + wv*4096 + jj*1024));
    }
    __syncthreads();
    if (ctep==7) {
      for (int z=tid; z<128*12; z+=256) {
        int r = z/12, j = 52 + (z - (z/12)*12);
        *(ushort*)((char*)sh2 + 16384 + r*128 + ((j*2) ^ ((r&7)<<4))) = 0;
      }
      __syncthreads();
    }
    #pragma unroll
    for (int kc=0;kc<2;kc++) {
      s16x8 af[4], bf2[4];
      #pragma unroll
      for (int mf=0;mf<4;mf++){
        int row = wr*64+mf*16+c16;
        af[mf] = *(const s16x8*)((const char*)sh2 + row*128 + ((((kc*32+g*8)*2)) ^ ((row&7)<<4)));
      }
      #pragma unroll
      for (int nf=0;nf<4;nf++){
        int row = wc*64+nf*16+c16;
        bf2[nf] = *(const s16x8*)((const char*)sh2 + 16384 + row*128 + ((((kc*32+g*8)*2)) ^ ((row&7)<<4)));
      }
      #pragma unroll
      for (int mf=0;mf<4;mf++)
        #pragma unroll
        for (int nf=0;nf<4;nf++)
          acc[mf][nf] = __builtin_amdgcn_mfma_f32_16x16x32_bf16(af[mf], bf2[nf], acc[mf][nf], 0,0,0);
    }
  }
  float* outp = kvp + (size_t)bnh*16384;
  #pragma unroll
  for (int mf=0;mf<4;mf++)
    #pragma unroll
    for (int nf=0;nf<4;nf++)
      #pragma unroll
      for (int reg=0;reg<4;reg++)
        outp[(size_t)(wr*64+mf*16+g*4+reg)*128 + wc*64+nf*16+c16] = acc[mf][nf][reg];
}

// ------- scan: st = st*cd + cst*kv_i ; kvrecT bf16 [dv][dk] -------
__global__ __launch_bounds__(256) void scan_kernel(const float* __restrict__ kvp,
                                                   ushort* __restrict__ kvrecT,
                                                   float* __restrict__ crosssc) {
  int bh = blockIdx.x;
  int b = bh>>3, h = bh&7;
  float Dh = 1.0f - exp2f(-5.0f-(float)h);
  float decay = logf(Dh);
  float cd = expf(decay*500.0f);
  float ls = (1.0f - expf(decay*500.0f))/(1.0f-Dh);
  float cst = expf(decay*499.0f)/ls;
  int tid=threadIdx.x;
  int vcol = tid&127, khalf = tid>>7;
  float st[64];
  #pragma unroll
  for (int i=0;i<64;i++) st[i]=0;
  float scale = 1.0f;
  __shared__ float colpart[2][128];
  __shared__ float sred[2];
  for (int n=0;n<8;n++) {
    int bnh = (b*8+n)*8+h;
    const float* src = kvp + (size_t)bnh*16384;
    ushort* rec = kvrecT + (size_t)bnh*16384;
    float inv = 1.0f/scale;
    float cs = 0;
    #pragma unroll
    for (int i=0;i<64;i++) {
      int kk = khalf*64+i;
      rec[(size_t)vcol*128+kk] = f2bf(st[i]*inv);
      st[i] = st[i]*cd + cst*src[(size_t)kk*128+vcol];
      cs += fabsf(st[i]);
    }
    if (tid==0) crosssc[bnh] = scale;
    colpart[khalf][vcol] = cs;
    __syncthreads();
    if (tid<128) colpart[0][tid] += colpart[1][tid];
    __syncthreads();
    float m = (tid<128)? colpart[0][tid] : 0.0f;
    #pragma unroll
    for (int o=32;o;o>>=1) m = fmaxf(m,__shfl_xor(m,o));
    if (tid<128 && (tid&63)==0) sred[tid>>6]=m;
    __syncthreads();
    scale = fmaxf(fmaxf(sred[0],sred[1]),1.0f);
    __syncthreads();
  }
}

// ---- retention core, XCD-grouped grid ----
__global__ __launch_bounds__(256,4) void iout_mfma(const ushort* __restrict__ qr,
                                                   const ushort* __restrict__ kr,
                                                   const ushort* __restrict__ vT,
                                                   const ushort* __restrict__ kvrecT,
                                                   const float* __restrict__ crosssc,
                                                   const ushort* __restrict__ gbuf,
                                                   ushort* __restrict__ opre) {
  int ib = blockIdx.x;
  int x = ib&7, u = ib>>3;
  int rt = u&7;
  int bnh = x*32 + (u>>3);
  int h = bnh&7, n=(bnh>>3)&7, b=bnh>>6;
  size_t base = (size_t)(b*4000+n*500)*1024 + h*128;
  float Dh = 1.0f - exp2f(-5.0f-(float)h);
  float decay = logf(Dh);
  __shared__ ushort sh[20480];
  char* shb = (char*)sh;
  int tid = threadIdx.x;
  int wv = tid>>6, l = tid&63;
  int g = l>>4, c16 = l&15;
  int r_base = rt*64 + wv*16 + g*4;

  int qrow = rt*64 + wv*16 + c16; if (qrow>499) qrow=499;
  s16x8 aq[4];
  #pragma unroll
  for (int kc=0;kc<4;kc++)
    aq[kc] = *(const s16x8*)(qr + base + (size_t)qrow*1024 + kc*32 + g*8);

  int ktrow[4], ktofs[4], vtrow[4], vtofs[4];
  #pragma unroll
  for (int jj=0;jj<4;jj++){
    int i = wv*256 + jj*64 + l;
    int r_ = i>>4;  ktrow[jj]=r_;  ktofs[jj] = (((i&15)*16) ^ ((r_&7)<<4))>>1;
    int r2_ = i>>3; vtrow[jj]=r2_; vtofs[jj] = (((i&7)*16) ^ ((r2_&7)<<4))>>1;
  }
  const ushort* vTb = vT + (size_t)bnh*65536;

  f32x4 pv[8], cc[8];
  #pragma unroll
  for (int i=0;i<8;i++){
    #pragma unroll
    for (int j=0;j<4;j++){ pv[i][j]=0.0f; cc[i][j]=0.0f; }
  }
  float rowsum[4] = {0,0,0,0};

  for (int et=0; et<=rt; et++) {
    __syncthreads();
    #pragma unroll
    for (int jj=0;jj<4;jj++){
      int gr = et*64 + ktrow[jj]; if (gr>499) gr=499;
      gload16(kr + base + (size_t)gr*1024 + ktofs[jj], (ushort*)(shb + wv*4096 + jj*1024));
      gload16(vTb + (size_t)vtrow[jj]*512 + et*64 + vtofs[jj], (ushort*)(shb + 16384 + wv*4096 + jj*1024));
    }
    __syncthreads();
    f32x4 S[4];
    #pragma unroll
    for (int i=0;i<4;i++){ S[i][0]=0; S[i][1]=0; S[i][2]=0; S[i][3]=0; }
    __builtin_amdgcn_s_setprio(1);
    #pragma unroll
    for (int kc=0;kc<4;kc++) {
      #pragma unroll
      for (int ni=0;ni<4;ni++) {
        int krow = ni*16+c16;
        s16x8 bf = *(const s16x8*)(shb + krow*256 + ((((kc*32+g*8)*2)) ^ ((krow&7)<<4)));
        S[ni] = __builtin_amdgcn_mfma_f32_16x16x32_bf16(aq[kc], bf, S[ni], 0,0,0);
      }
    }
    __builtin_amdgcn_s_setprio(0);
    bool diag = (et==rt);
    #pragma unroll
    for (int ni=0;ni<4;ni++) {
      int e_rel = et*64 + ni*16 + c16;
      #pragma unroll
      for (int reg=0;reg<4;reg++) {
        float p = S[ni][reg];
        if (diag && e_rel > r_base+reg) p = 0.0f;
        rowsum[reg] += fabsf(p);
        int prow = wv*16 + g*4 + reg;
        *(ushort*)(shb + 32768 + prow*128 + (((ni*16+c16)*2) ^ ((prow&7)<<4))) = f2bf(p);
      }
    }
    __builtin_amdgcn_s_setprio(1);
    #pragma unroll
    for (int kc=0;kc<2;kc++) {
      int prow = wv*16 + c16;
      s16x8 pa = *(const s16x8*)(shb + 32768 + prow*128 + ((((kc*32+g*8)*2)) ^ ((prow&7)<<4)));
      #pragma unroll
      for (int nf=0;nf<8;nf++) {
        int vrow = nf*16+c16;
        s16x8 vb = *(const s16x8*)(shb + 16384 + vrow*128 + ((((kc*32+g*8)*2)) ^ ((vrow&7)<<4)));
        pv[nf] = __builtin_amdgcn_mfma_f32_16x16x32_bf16(pa, vb, pv[nf], 0,0,0);
      }
    }
    __builtin_amdgcn_s_setprio(0);
  }
  #pragma unroll
  for (int reg=0;reg<4;reg++) {
    float s = rowsum[reg];
    s += __shfl_xor(s,1); s += __shfl_xor(s,2); s += __shfl_xor(s,4); s += __shfl_xor(s,8);
    rowsum[reg] = s;
  }
  __syncthreads();
  #pragma unroll
  for (int jj=0;jj<8;jj++){
    int i = wv*512 + jj*64 + l;
    int r_ = i>>4;
    int ofs = (((i&15)*16) ^ ((r_&7)<<4))>>1;
    gload16(kvrecT + (size_t)bnh*16384 + (size_t)r_*128 + ofs, (ushort*)(shb + wv*8192 + jj*1024));
  }
  __syncthreads();
  __builtin_amdgcn_s_setprio(1);
  #pragma unroll
  for (int kc=0;kc<4;kc++) {
    #pragma unroll
    for (int nf=0;nf<8;nf++) {
      int krow = nf*16+c16;
      s16x8 bb = *(const s16x8*)(shb + krow*256 + ((((kc*32+g*8)*2)) ^ ((krow&7)<<4)));
      cc[nf] = __builtin_amdgcn_mfma_f32_16x16x32_bf16(aq[kc], bb, cc[nf], 0,0,0);
    }
  }
  __builtin_amdgcn_s_setprio(0);
  float cs = crosssc[bnh];
  float lsum = (1.0f-expf(decay*500.0f))/(1.0f-Dh);
  float ed = expf(decay);
  #pragma unroll
  for (int reg=0;reg<4;reg++) {
    int rr = r_base + reg;
    if (rr < 500) {
      float rs = (1.0f-expf(decay*(float)(rr+1)))/(1.0f-Dh);
      float rsr = rsqrtf(rs);
      float is = fmaxf(1.0f, rowsum[reg]*rsr);
      float all = fmaxf(is, cs);
      float qid = ed*lsum*rsr;
      float fi = rsr/all;
      float fc = qid*(cs/all);
      float o[8]; float ssq = 0.0f;
      #pragma unroll
      for (int nf=0;nf<8;nf++){ o[nf] = pv[nf][reg]*fi + cc[nf][reg]*fc; ssq += o[nf]*o[nf]; }
      ssq += __shfl_xor(ssq,1); ssq += __shfl_xor(ssq,2); ssq += __shfl_xor(ssq,4); ssq += __shfl_xor(ssq,8);
      float rmss = rsqrtf(ssq*(1.0f/128.0f)+1e-6f);
      size_t rowoff = (size_t)(b*4000+n*500+rr)*1024 + h*128;
      #pragma unroll
      for (int nf=0;nf<8;nf++){
        float gv = bfu(gbuf[rowoff + nf*16 + c16]);
        float sg = gv/(1.0f+expf(-gv));
        opre[rowoff + nf*16 + c16] = f2bf(sg*o[nf]*rmss);
      }
    }
  }
}

extern "C" void kernel_launch(void* const* d_in, const int* in_sizes, int n_in,
                              void* d_out, int out_size, void* d_ws, size_t ws_size,
                              hipStream_t stream) {
  const float* x     = (const float*)d_in[0];
  const float* gamma = (const float*)d_in[1];
  const float* beta  = (const float*)d_in[2];
  const float* Wq    = (const float*)d_in[3];
  const float* Wk    = (const float*)d_in[4];
  const float* Wv    = (const float*)d_in[5];
  const float* Wg    = (const float*)d_in[6];
  const float* Wo    = (const float*)d_in[7];
  float* out = (float*)d_out;

  char* ws = (char*)d_ws;
  size_t off = 0;
  auto alloc = [&](size_t bytes)->void* { void* p = ws+off; off += (bytes+255)&~(size_t)255; return p; };
  const size_t BT1024 = (size_t)16000*1024;
  ushort* xln  = (ushort*)alloc(BT1024*2);   // reused: kvp (fp32, 16.8MB) then opre
  ushort* q    = (ushort*)alloc(BT1024*2);
  ushort* k    = (ushort*)alloc(BT1024*2);
  ushort* g    = (ushort*)alloc(BT1024*2);
  // NOTE: WqT..WgT MUST be contiguous (fused GEMM treats them as one [4096][1024])
  ushort* WqT  = (ushort*)alloc((size_t)1024*1024*2);
  ushort* WkT  = (ushort*)alloc((size_t)1024*1024*2);
  ushort* WvT  = (ushort*)alloc((size_t)1024*1024*2);
  ushort* WgT  = (ushort*)alloc((size_t)1024*1024*2);
  ushort* WoT  = (ushort*)alloc((size_t)1024*1024*2);
  uint* cstab  = (uint*)alloc((size_t)4000*128*4);
  ushort* kT   = (ushort*)alloc((size_t)256*65536*2);
  ushort* vT   = (ushort*)alloc((size_t)256*65536*2);
  ushort* kvrecT=(ushort*)alloc((size_t)256*16384*2);
  float* crosssc = (float*)alloc(256*4);
  (void)ws_size; (void)in_sizes; (void)n_in; (void)out_size;

  ln_kernel<<<16000,256,0,stream>>>(x,gamma,beta,xln);
  sincos_kernel<<<1000,256,0,stream>>>(cstab);
  dim3 tt(16,16,5);
  f2bf_t_all<<<tt,256,0,stream>>>(Wq,Wk,Wv,Wg,Wo, WqT,WkT,WvT,WgT,WoT);

  // one fused projection GEMM: BT = [WqT;WkT;WvT;WgT] (contiguous)
  gemm_proj<<<4000,256,0,stream>>>(xln, WqT, q, k, g, kT, vT, cstab);

  float* kvp = (float*)xln;   // xln dead after projections
  kv_mfma<<<256,256,0,stream>>>(kT,vT,kvp);
  scan_kernel<<<32,256,0,stream>>>(kvp,kvrecT,crosssc);

  ushort* opre = xln;         // kvp dead after scan
  iout_mfma<<<2048,256,0,stream>>>(q,k,vT,kvrecT,crosssc,g,opre);

  gemm_out<<<1000,256,0,stream>>>(opre,WoT,out);
}